// Round 8
// baseline (596.964 us; speedup 1.0000x reference)
//
#include <hip/hip_runtime.h>
#include <cstddef>

// ============================================================================
// MultiWaveletTransform — algebraic refactor, all heavy math on MFMA.
// Round 8: dispatch-graph compaction on top of R7's verified 584us config.
// (1) conv_xh deleted: modmfma reads X fp32 directly (identical rounding)
//     and writes Xh back for branch-1 (each X element is read exactly once).
// (2) sgemm_stage2 (F from MEMORY — not the slow inline-trig variant) fused
//     into the modmfma dispatch as extra blocks. 11 -> 9 dispatches.
// ============================================================================

#define PI_D 3.14159265358979323846

typedef _Float16 h8 __attribute__((ext_vector_type(8)));
typedef _Float16 h4 __attribute__((ext_vector_type(4)));
typedef float f4 __attribute__((ext_vector_type(4)));

#define MFMA16(a, b, c) __builtin_amdgcn_mfma_f32_16x16x32_f16(a, b, c, 0, 0, 0)

// ---------------- dispatch 1: F + tables + vectors + c-vecs ----------------
// blocks [0,1024): F        [1024,2048): Cm/Smn/CmT/SmT tables
// [2048,2176): v1/w2/w3     [2176,2560): c1/c2/c3 = F^T b
__global__ __launch_bounds__(256) void megafill_k(
    float* __restrict__ F, _Float16* __restrict__ Cmh, _Float16* __restrict__ Smnh,
    _Float16* __restrict__ CmTh, _Float16* __restrict__ SmTh,
    float* __restrict__ v1, float* __restrict__ w2, float* __restrict__ w3,
    const float* __restrict__ b1, const float* __restrict__ b2,
    const float* __restrict__ b3, float* __restrict__ c1, float* __restrict__ c2,
    float* __restrict__ c3) {
  const int blk = blockIdx.x;
  const int tid = threadIdx.x;
  if (blk < 1024) {
    int idx = blk * 256 + tid;
    int k = idx >> 9, m = idx & 511;
    int a = (k * (2 * m + 1)) & 2047;
    float ang = (float)(a * (PI_D / 1024.0));
    float s = (k == 0) ? 0.04419417382415922f : 0.0625f;
    F[idx] = s * cosf(ang);
  } else if (blk < 2048) {
    int idx = (blk - 1024) * 256 + tid;
    int t = idx >> 9, v = idx & 511;
    int a = (t * (2 * v + 1)) & 2047;
    float ang = (float)(a * (PI_D / 1024.0));
    float c = cosf(ang), s = sinf(ang);
    Cmh[idx] = (_Float16)c;
    Smnh[idx] = (_Float16)(-s);
    CmTh[v * 512 + t] = (_Float16)c;
    SmTh[v * 512 + t] = (_Float16)s;
  } else if (blk < 2176) {
    int n = (blk - 2048) * 256 + tid;
    const double s1 = 0.005524271728019903;
    const double s2 = 0.0078125;
    double th = (2 * n + 1) * (PI_D / 65536.0);
    double c = cos(th), s = sin(th);
    double Dr = 1.0 - c, Di = -s;
    double dd = Dr * Dr + Di * Di;
    double Nr = 1.0, Ni = (n & 1) ? 1.0 : -1.0;
    double vre = (Nr * Dr + Ni * Di) / dd;
    v1[n] = (float)(s2 * vre + (s1 - s2));
    int m64 = (2 * n + 1) & 2047;
    double a64 = m64 * (PI_D / 1024.0);
    double D64r = 1.0 - cos(a64), D64i = -sin(a64);
    double d64 = D64r * D64r + D64i * D64i;
    double Gr = (Nr * D64r + Ni * D64i) / d64;
    double Gi = (Ni * D64r - Nr * D64i) / d64;
    int m32 = (2 * n + 1) & 4095;
    double a32 = m32 * (PI_D / 2048.0);
    double S32nr = 1.0 - cos(a32), S32ni = -sin(a32);
    double S32r = (S32nr * Dr + S32ni * Di) / dd;
    double S32i = (S32ni * Dr - S32nr * Di) / dd;
    w2[n] = (float)(s2 * (S32r * Gr - S32i * Gi) + (s1 - s2));
    int m16 = (2 * n + 1) & 8191;
    double a16 = m16 * (PI_D / 4096.0);
    double S16nr = 1.0 - cos(a16), S16ni = -sin(a16);
    double S16r = (S16nr * Dr + S16ni * Di) / dd;
    double S16i = (S16ni * Dr - S16nr * Di) / dd;
    w3[n] = (float)(s2 * (S16r * Gr - S16i * Gi) + (s1 - s2));
  } else {
    // c_i[l] = sum_m F[m][l] * b_i[m], one wave per (branch,l)
    int gid = (blk - 2176) * 4 + (tid >> 6);
    int lane = tid & 63;
    int branch = gid >> 9;
    int l = gid & 511;
    int K = 512 >> branch;
    const float* b = (branch == 0) ? b1 : (branch == 1) ? b2 : b3;
    float acc = 0.f;
    for (int m = lane; m < K; m += 64) {
      int a = (m * (2 * l + 1)) & 2047;
      float s = (m == 0) ? 0.04419417382415922f : 0.0625f;
      acc += s * cosf((float)(a * (PI_D / 1024.0))) * b[m];
    }
#pragma unroll
    for (int o = 32; o > 0; o >>= 1) acc += __shfl_down(acc, o, 64);
    if (lane == 0) {
      float* c = (branch == 0) ? c1 : (branch == 1) ? c2 : c3;
      c[l] = acc;
    }
  }
}

// ---------------- small MFMA GEMM for precompute (device fn) ----------------
// C[m][n] = sum_k A'[k][m] * B[k][n]  (B always [K][N] fp32, transpose-staged;
// A: transA=1 -> A[k][m], transA=0 -> A[m][k]).  Out fp32 or f16*scale, ldc=512.
__device__ void sgemm_dev(_Float16* As, _Float16* Bs, int bx, int by,
                          const float* __restrict__ A, int lda, int transA,
                          const float* __restrict__ B, int ldb,
                          float* __restrict__ Cf, _Float16* __restrict__ C16,
                          int K, float scale) {
  const int tid = threadIdx.x;
  const int lane = tid & 63;
  const int wm = (tid >> 6) & 1, wn = tid >> 7;
  const int m0 = by * 128, n0 = bx * 128;
  const int fm = lane & 15, fko = (lane >> 4) * 8;
  f4 acc[4][4] = {};
  for (int k0 = 0; k0 < K; k0 += 32) {
    if (transA) {
#pragma unroll
      for (int i = 0; i < 4; i++) {
        int idx4 = tid + i * 256;
        int kk = idx4 & 31, mc = (idx4 >> 5) * 4;
        float4 v = *(const float4*)&A[(size_t)(k0 + kk) * lda + m0 + mc];
        As[(mc + 0) * 40 + kk] = (_Float16)v.x;
        As[(mc + 1) * 40 + kk] = (_Float16)v.y;
        As[(mc + 2) * 40 + kk] = (_Float16)v.z;
        As[(mc + 3) * 40 + kk] = (_Float16)v.w;
      }
    } else {
#pragma unroll
      for (int i = 0; i < 4; i++) {
        int idx4 = tid + i * 256;
        int mm = idx4 >> 3, kc = (idx4 & 7) * 4;
        float4 v = *(const float4*)&A[(size_t)(m0 + mm) * lda + k0 + kc];
        h4 o;
        o[0] = (_Float16)v.x; o[1] = (_Float16)v.y; o[2] = (_Float16)v.z; o[3] = (_Float16)v.w;
        *(h4*)&As[mm * 40 + kc] = o;
      }
    }
#pragma unroll
    for (int i = 0; i < 4; i++) {
      int idx4 = tid + i * 256;
      int kk = idx4 & 31, nc = (idx4 >> 5) * 4;
      float4 v = *(const float4*)&B[(size_t)(k0 + kk) * ldb + n0 + nc];
      Bs[(nc + 0) * 40 + kk] = (_Float16)v.x;
      Bs[(nc + 1) * 40 + kk] = (_Float16)v.y;
      Bs[(nc + 2) * 40 + kk] = (_Float16)v.z;
      Bs[(nc + 3) * 40 + kk] = (_Float16)v.w;
    }
    __syncthreads();
    h8 af[4], bf[4];
#pragma unroll
    for (int i = 0; i < 4; i++) af[i] = *(const h8*)&As[(wm * 64 + i * 16 + fm) * 40 + fko];
#pragma unroll
    for (int j = 0; j < 4; j++) bf[j] = *(const h8*)&Bs[(wn * 64 + j * 16 + fm) * 40 + fko];
#pragma unroll
    for (int i = 0; i < 4; i++)
#pragma unroll
      for (int j = 0; j < 4; j++) acc[i][j] = MFMA16(af[i], bf[j], acc[i][j]);
    __syncthreads();
  }
  const int er = (lane >> 4) * 4, ec = lane & 15;
#pragma unroll
  for (int i = 0; i < 4; i++) {
    int gr0 = m0 + wm * 64 + i * 16 + er;
#pragma unroll
    for (int j = 0; j < 4; j++) {
      int gc = n0 + wn * 64 + j * 16 + ec;
#pragma unroll
      for (int r = 0; r < 4; r++) {
        size_t off = (size_t)(gr0 + r) * 512 + gc;
        if (C16) C16[off] = (_Float16)(acc[i][j][r] * scale);
        else Cf[off] = acc[i][j][r];
      }
    }
  }
}

// stage 1: Pst = W1^T F (16 blk) | Q2 = W2 F1 (8 blk) | Q3 = W3 F2 (4 blk)
__global__ __launch_bounds__(256) void sgemm_stage1_k(
    const float* __restrict__ W1, const float* __restrict__ W2,
    const float* __restrict__ W3, const float* __restrict__ F,
    float* __restrict__ Pst, float* __restrict__ Q2, float* __restrict__ Q3) {
  __shared__ _Float16 As[128 * 40];
  __shared__ _Float16 Bs[128 * 40];
  int id = blockIdx.x;
  if (id < 16) {
    sgemm_dev(As, Bs, id & 3, id >> 2, W1, 512, 1, F, 512, Pst, nullptr, 512, 1.f);
  } else if (id < 24) {
    int j = id - 16;
    sgemm_dev(As, Bs, j & 3, j >> 2, W2, 256, 0, F, 512, Q2, nullptr, 256, 1.f);
  } else {
    int j = id - 24;
    sgemm_dev(As, Bs, j & 3, j >> 2, W3, 128, 0, F, 512, Q3, nullptr, 128, 1.f);
  }
}

// ---------------- modulation device fn (reads X fp32, writes Xh back) -------
__device__ void modmfma_dev(char* smemraw, const float* __restrict__ X,
                            _Float16* __restrict__ Xh, _Float16* __restrict__ zc,
                            _Float16* __restrict__ zs, int vp, int l0) {
  _Float16* Bs = (_Float16*)smemraw;                 // 256*72 h = 36864 B
  _Float16* Ac = (_Float16*)(smemraw + 36864);       // 32*72 h = 4608 B
  _Float16* As = (_Float16*)(smemraw + 41472);       // 32*72 h = 4608 B
  const int tid = threadIdx.x;
  const int lane = tid & 63;
  const int wid = tid >> 6;
  const float sc = 0.0078125f;
  {  // stage X transposed (fp32 -> fp16 inline; write Xh back for branch-1)
    int r = lane;
    int u = r & 31;
    int n = (r < 32) ? ((u << 10) + vp) : ((u << 10) + 1023 - vp);
    const float* src = X + (size_t)n * 512 + l0 + wid * 64;
    _Float16* xdst = Xh + (size_t)n * 512 + l0 + wid * 64;
#pragma unroll
    for (int i = 0; i < 8; i++) {
      float4 a = *(const float4*)(src + i * 8);
      float4 b = *(const float4*)(src + i * 8 + 4);
      h8 v;
      v[0] = (_Float16)a.x; v[1] = (_Float16)a.y; v[2] = (_Float16)a.z; v[3] = (_Float16)a.w;
      v[4] = (_Float16)b.x; v[5] = (_Float16)b.y; v[6] = (_Float16)b.z; v[7] = (_Float16)b.w;
      *(h8*)(xdst + i * 8) = v;
      int lb = wid * 64 + i * 8;
#pragma unroll
      for (int e = 0; e < 8; e++) Bs[(lb + e) * 72 + r] = v[e];
    }
  }
  for (int idx = tid; idx < 2048; idx += 256) {  // tables, trig inline
    int kk = idx & 63, j = idx >> 6;
    int u = kk & 31;
    int n = (kk < 32) ? ((u << 10) + vp) : ((u << 10) + 1023 - vp);
    int a = (j * (2 * n + 1)) & 131071;
    float sv, cv;
    __sincosf((float)(a * (PI_D / 65536.0)), &sv, &cv);
    Ac[j * 72 + kk] = (_Float16)(cv * sc);
    As[j * 72 + kk] = (_Float16)(((kk < 32) ? sv : -sv) * sc);
  }
  __syncthreads();
  const int fm = lane & 15, fko = (lane >> 4) * 8;
  f4 accc[2][4] = {};
  f4 accs[2][4] = {};
#pragma unroll
  for (int ks = 0; ks < 2; ks++) {
    int ko = ks * 32 + fko;
    h8 afc[2], afs[2], bf[4];
#pragma unroll
    for (int i = 0; i < 2; i++) {
      afc[i] = *(const h8*)&Ac[(i * 16 + fm) * 72 + ko];
      afs[i] = *(const h8*)&As[(i * 16 + fm) * 72 + ko];
    }
#pragma unroll
    for (int j = 0; j < 4; j++)
      bf[j] = *(const h8*)&Bs[(wid * 64 + j * 16 + fm) * 72 + ko];
#pragma unroll
    for (int i = 0; i < 2; i++)
#pragma unroll
      for (int j = 0; j < 4; j++) {
        accc[i][j] = MFMA16(afc[i], bf[j], accc[i][j]);
        accs[i][j] = MFMA16(afs[i], bf[j], accs[i][j]);
      }
  }
  const int er = (lane >> 4) * 4, ec = lane & 15;
#pragma unroll
  for (int i = 0; i < 2; i++)
#pragma unroll
    for (int j = 0; j < 4; j++)
#pragma unroll
      for (int r = 0; r < 4; r++) {
        int row = i * 16 + er + r;
        int col = l0 + wid * 64 + j * 16 + ec;
        size_t off = (size_t)vp * 16384 + row * 512 + col;
        zc[off] = (_Float16)accc[i][j][r];
        zs[off] = (_Float16)accs[i][j][r];
      }
}

// ---------------- dispatch 3: modulation (+X conv +Xh writeback) + sgemm2 ---
// blocks [0,1024): modmfma (vp = blk>>1, l0 = (blk&1)*256)
// [1024,1072): M1T/M2T/M3T sandwich stage 2 (F from memory)
__global__ __launch_bounds__(256) void mega3_k(
    const float* __restrict__ X, _Float16* __restrict__ Xh,
    _Float16* __restrict__ zc, _Float16* __restrict__ zs,
    const float* __restrict__ F, const float* __restrict__ Pst,
    const float* __restrict__ Q2, const float* __restrict__ Q3,
    _Float16* __restrict__ M1T, _Float16* __restrict__ M2T,
    _Float16* __restrict__ M3T) {
  __shared__ __align__(16) char smem[46080];
  const int blk = blockIdx.x;
  if (blk < 1024) {
    modmfma_dev(smem, X, Xh, zc, zs, blk >> 1, (blk & 1) * 256);
  } else {
    _Float16* As = (_Float16*)smem;
    _Float16* Bs = (_Float16*)(smem + 128 * 40 * 2);
    int id = blk - 1024;
    if (id < 16) {         // M1T = Pst^T F
      sgemm_dev(As, Bs, id & 3, id >> 2, Pst, 512, 1, F, 512, nullptr, M1T, 512, 1.f);
    } else if (id < 32) {  // M2T = F^T Q2
      int j = id - 16;
      sgemm_dev(As, Bs, j & 3, j >> 2, F, 512, 1, Q2, 512, nullptr, M2T, 256, 0.0078125f);
    } else {               // M3T = F^T Q3
      int j = id - 32;
      sgemm_dev(As, Bs, j & 3, j >> 2, F, 512, 1, Q3, 512, nullptr, M3T, 128, 0.0078125f);
    }
  }
}

// ---------------- fp16 tiled transpose, two jobs per launch ----------------
__global__ __launch_bounds__(256) void transpose2_h_k(
    const _Float16* __restrict__ in0, _Float16* __restrict__ out0, int C0,
    const _Float16* __restrict__ in1, _Float16* __restrict__ out1, int C1,
    int xsplit, int R) {
  __shared__ _Float16 t[64][66];
  const _Float16* in;
  _Float16* out;
  int C, bx;
  if ((int)blockIdx.x < xsplit) { in = in0; out = out0; C = C0; bx = blockIdx.x; }
  else { in = in1; out = out1; C = C1; bx = blockIdx.x - xsplit; }
  int tid = threadIdx.x;
  int bxo = bx * 64;
  int by = blockIdx.y * 64;
  int cx = (tid & 15) * 4;
  int ry = tid >> 4;
#pragma unroll
  for (int p = 0; p < 4; p++) {
    int r = ry + p * 16;
    h4 v = *(const h4*)&in[(size_t)(by + r) * C + bxo + cx];
    t[r][cx + 0] = v[0]; t[r][cx + 1] = v[1]; t[r][cx + 2] = v[2]; t[r][cx + 3] = v[3];
  }
  __syncthreads();
#pragma unroll
  for (int p = 0; p < 4; p++) {
    int r2 = ry + p * 16;
    h4 v;
    v[0] = t[cx + 0][r2]; v[1] = t[cx + 1][r2]; v[2] = t[cx + 2][r2]; v[3] = t[cx + 3][r2];
    *(h4*)&out[(size_t)(bxo + r2) * R + by + cx] = v;
  }
}

// ---------------- main f16 MFMA GEMM (device fn, async16 staging) -----------
__device__ __forceinline__ void async16(const _Float16* g, _Float16* l) {
  __builtin_amdgcn_global_load_lds((const __attribute__((address_space(1))) void*)g,
                                   (__attribute__((address_space(3))) void*)l, 16, 0, 0);
}

template <int MODE>
__device__ void gemm_dev(_Float16* As, _Float16* Bs, int bx, int by,
                         const _Float16* __restrict__ A1, const _Float16* __restrict__ A2,
                         const _Float16* __restrict__ B1, const _Float16* __restrict__ B2,
                         void* __restrict__ C1, void* __restrict__ C2, int ldc, int coff,
                         const float* __restrict__ u, const float* __restrict__ wvec,
                         int sb, int tb) {
  constexpr bool DA = (MODE == 1 || MODE == 2);
  constexpr bool DB = (MODE == 1);
  const int tid = threadIdx.x;
  const int lane = tid & 63;
  const int wm = (tid >> 6) & 1, wn = tid >> 7;
  const int m0 = by * 128, n0 = bx * 128;
  const int srow = tid >> 2, scol = (tid & 3) * 8;
  const int mask = (1 << sb) - 1;
  f4 acc[4][4] = {};
  f4 acc2[4][4] = {};
  const int fm = lane & 15, fko = (lane >> 4) * 8;
  for (int k0 = 0; k0 < 512; k0 += 32) {
#pragma unroll
    for (int i = 0; i < 2; i++) {
      int r = m0 + i * 64 + srow;
      int pr = ((r >> sb) << tb) | (r & mask);
      async16(A1 + (size_t)pr * 512 + k0 + scol, &As[i * 2048 + tid * 8]);
      if constexpr (DA)
        async16(A2 + (size_t)pr * 512 + k0 + scol, &As[4096 + i * 2048 + tid * 8]);
      int rb = n0 + i * 64 + srow;
      async16(B1 + (size_t)rb * 512 + k0 + scol, &Bs[i * 2048 + tid * 8]);
      if constexpr (DB)
        async16(B2 + (size_t)rb * 512 + k0 + scol, &Bs[4096 + i * 2048 + tid * 8]);
    }
    __syncthreads();
    h8 af[4], bf[4], af2[4], bf2[4];
#pragma unroll
    for (int i = 0; i < 4; i++) {
      int ro = (wm * 64 + i * 16 + fm) * 32 + fko;
      af[i] = *(const h8*)&As[ro];
      if constexpr (DA) af2[i] = *(const h8*)&As[4096 + ro];
    }
#pragma unroll
    for (int j = 0; j < 4; j++) {
      int co = (wn * 64 + j * 16 + fm) * 32 + fko;
      bf[j] = *(const h8*)&Bs[co];
      if constexpr (DB) bf2[j] = *(const h8*)&Bs[4096 + co];
    }
#pragma unroll
    for (int i = 0; i < 4; i++)
#pragma unroll
      for (int j = 0; j < 4; j++) {
        acc[i][j] = MFMA16(af[i], bf[j], acc[i][j]);
        if constexpr (MODE == 1) acc[i][j] = MFMA16(af2[i], bf2[j], acc[i][j]);
        if constexpr (MODE == 2) acc2[i][j] = MFMA16(af2[i], bf[j], acc2[i][j]);
      }
    __syncthreads();
  }
  const int er = (lane >> 4) * 4, ec = lane & 15;
#pragma unroll
  for (int i = 0; i < 4; i++) {
    int gr0 = m0 + wm * 64 + i * 16 + er;
#pragma unroll
    for (int j = 0; j < 4; j++) {
      int gc = n0 + wn * 64 + j * 16 + ec;
#pragma unroll
      for (int r = 0; r < 4; r++) {
        size_t off = (size_t)(gr0 + r) * ldc + coff + gc;
        if constexpr (MODE == 3) {
          ((float*)C1)[off] = acc[i][j][r] + u[gr0 + r] * wvec[gc];
        } else if constexpr (MODE == 2) {
          ((_Float16*)C1)[off] = (_Float16)acc[i][j][r];
          ((_Float16*)C2)[off] = (_Float16)acc2[i][j][r];
        } else if constexpr (MODE == 1) {
          float v = acc[i][j][r];
          if ((gr0 + r) == 0 && gc < 512) v *= 0.5f;  // fused s_0^2 fixup (t=0,j=0)
          ((_Float16*)C1)[off] = (_Float16)v;
        } else {
          ((_Float16*)C1)[off] = (_Float16)acc[i][j][r];
        }
      }
    }
  }
}

template <int MODE>
__global__ __launch_bounds__(256) void mfma_gemm_k(
    const _Float16* __restrict__ A1, const _Float16* __restrict__ A2,
    const _Float16* __restrict__ B1, const _Float16* __restrict__ B2,
    void* __restrict__ C1, void* __restrict__ C2, int ldc, int coff,
    const float* __restrict__ u, const float* __restrict__ wvec, int sb, int tb) {
  __shared__ __align__(16) _Float16 As[((MODE == 1 || MODE == 2) ? 2 : 1) * 4096];
  __shared__ __align__(16) _Float16 Bs[(MODE == 1 ? 2 : 1) * 4096];
  gemm_dev<MODE>(As, Bs, blockIdx.x, blockIdx.y, A1, A2, B1, B2, C1, C2, ldc, coff,
                 u, wvec, sb, tb);
}

// Y2 = Zh M2T (by<128) | Y3 = Zh[j<16] M3T (by in [128,192))
// | out1 = X M1 + v1 c1^T (by >= 192)
__global__ __launch_bounds__(256) void gemm_trio_k(
    const _Float16* __restrict__ Zh, const _Float16* __restrict__ M2T,
    const _Float16* __restrict__ M3T, _Float16* __restrict__ Y2,
    _Float16* __restrict__ Y3, const _Float16* __restrict__ Xh,
    const _Float16* __restrict__ M1T, float* __restrict__ out,
    const float* __restrict__ v1, const float* __restrict__ c1) {
  __shared__ __align__(16) _Float16 As[4096];
  __shared__ __align__(16) _Float16 Bs[4096];
  int by = blockIdx.y;
  if (by < 128)
    gemm_dev<0>(As, Bs, blockIdx.x, by, Zh, nullptr, M2T, nullptr, Y2, nullptr,
                512, 0, nullptr, nullptr, 30, 30);
  else if (by < 192)
    gemm_dev<0>(As, Bs, blockIdx.x, by - 128, Zh, nullptr, M3T, nullptr, Y3,
                nullptr, 512, 0, nullptr, nullptr, 4, 5);
  else
    gemm_dev<3>(As, Bs, blockIdx.x, by - 192, Xh, nullptr, M1T, nullptr, out,
                nullptr, 1536, 0, v1, c1, 30, 30);
}

// Pc2/Ps2 = CmT/SmT . Y2T (bx<128, ldc 16384) | Pc3/Ps3 = . Y3T (bx>=128, ldc 8192)
__global__ __launch_bounds__(256) void gemm2_pair_k(
    const _Float16* __restrict__ CmTh, const _Float16* __restrict__ SmTh,
    const _Float16* __restrict__ Y2T, const _Float16* __restrict__ Y3T,
    _Float16* __restrict__ Pc2, _Float16* __restrict__ Ps2,
    _Float16* __restrict__ Pc3, _Float16* __restrict__ Ps3) {
  __shared__ __align__(16) _Float16 As[2 * 4096];
  __shared__ __align__(16) _Float16 Bs[4096];
  if ((int)blockIdx.x < 128)
    gemm_dev<2>(As, Bs, blockIdx.x, blockIdx.y, CmTh, SmTh, Y2T, nullptr, Pc2, Ps2,
                16384, 0, nullptr, nullptr, 30, 30);
  else
    gemm_dev<2>(As, Bs, blockIdx.x - 128, blockIdx.y, CmTh, SmTh, Y3T, nullptr, Pc3,
                Ps3, 8192, 0, nullptr, nullptr, 30, 30);
}

// ---------------- MFMA demodulation (tables inline, both branches fused) ----
template <int JC>
__device__ void demod_dev(char* smemraw, const _Float16* __restrict__ Pc,
                          const _Float16* __restrict__ Ps,
                          const float* __restrict__ wv, const float* __restrict__ cw,
                          float* __restrict__ out, int coff) {
  constexpr int K2 = 2 * JC;
  constexpr int ST = K2 + 8;
  _Float16* Bs = (_Float16*)smemraw;                          // 256*ST
  _Float16* At = (_Float16*)(smemraw + (size_t)256 * ST * 2); // 64*ST
  const int tid = threadIdx.x;
  const int lane = tid & 63;
  const int wid = tid >> 6;
  const int vp = blockIdx.y;
  const int l0 = blockIdx.x * 256;
  {  // stage P transposed
    constexpr int CPL = 64 / K2;
    int r = lane & (K2 - 1);
    int chunk = wid * CPL + (CPL == 1 ? 0 : (lane >> 5));
    int lb = chunk * K2;
    const _Float16* src = (r < JC ? Pc + (size_t)vp * (JC * 512) + r * 512
                                  : Ps + (size_t)vp * (JC * 512) + (r - JC) * 512) +
                          l0 + lb;
#pragma unroll
    for (int i = 0; i < K2 / 8; i++) {
      h8 v = *(const h8*)(src + i * 8);
#pragma unroll
      for (int e = 0; e < 8; e++) Bs[(lb + i * 8 + e) * ST + r] = v[e];
    }
  }
  for (int idx = tid; idx < 64 * K2; idx += 256) {  // tables, trig inline
    int kk = idx & (K2 - 1), m = idx / K2;
    int ab = m >> 5, u = m & 31;
    int n = ab ? ((u << 10) + 1023 - vp) : ((u << 10) + vp);
    int twon = 2 * n + 1;
    float val;
    if (kk < JC) {
      int a = (kk * twon) & 131071;
      val = cosf((float)(a * (PI_D / 65536.0)));
    } else {
      int a = ((kk - JC) * twon) & 131071;
      float sv = sinf((float)(a * (PI_D / 65536.0)));
      val = ab ? sv : -sv;
    }
    At[m * ST + kk] = (_Float16)val;
  }
  __syncthreads();
  const int fm = lane & 15, fko = (lane >> 4) * 8;
  f4 acc[4][4] = {};
#pragma unroll
  for (int ks = 0; ks < K2 / 32; ks++) {
    int ko = ks * 32 + fko;
    h8 af[4], bf[4];
#pragma unroll
    for (int i = 0; i < 4; i++) af[i] = *(const h8*)&At[(i * 16 + fm) * ST + ko];
#pragma unroll
    for (int j = 0; j < 4; j++) bf[j] = *(const h8*)&Bs[(wid * 64 + j * 16 + fm) * ST + ko];
#pragma unroll
    for (int i = 0; i < 4; i++)
#pragma unroll
      for (int j = 0; j < 4; j++) acc[i][j] = MFMA16(af[i], bf[j], acc[i][j]);
  }
  const int er = (lane >> 4) * 4, ec = lane & 15;
#pragma unroll
  for (int i = 0; i < 4; i++)
#pragma unroll
    for (int j = 0; j < 4; j++) {
      int col = l0 + wid * 64 + j * 16 + ec;
      float cl = cw[col];
#pragma unroll
      for (int r = 0; r < 4; r++) {
        int m = i * 16 + er + r;
        int ab = m >> 5, u = m & 31;
        int n = ab ? ((u << 10) + 1023 - vp) : ((u << 10) + vp);
        out[(size_t)n * 1536 + coff + col] = acc[i][j][r] + wv[n] * cl;
      }
    }
}

__global__ __launch_bounds__(256) void demod_pair_k(
    const _Float16* __restrict__ Pc2, const _Float16* __restrict__ Ps2,
    const float* __restrict__ w2v, const float* __restrict__ c2,
    const _Float16* __restrict__ Pc3, const _Float16* __restrict__ Ps3,
    const float* __restrict__ w3v, const float* __restrict__ c3,
    float* __restrict__ out) {
  __shared__ __align__(16) char smem[256 * 72 * 2 + 64 * 72 * 2];  // 46080 B
  if (blockIdx.z == 0)
    demod_dev<32>(smem, Pc2, Ps2, w2v, c2, out, 512);
  else
    demod_dev<16>(smem, Pc3, Ps3, w3v, c3, out, 1024);
}

// ---------------- launch ----------------
extern "C" void kernel_launch(void* const* d_in, const int* in_sizes, int n_in,
                              void* d_out, int out_size, void* d_ws, size_t ws_size,
                              hipStream_t stream) {
  const float* X  = (const float*)d_in[0];
  const float* W1 = (const float*)d_in[1];
  const float* b1 = (const float*)d_in[2];
  const float* W2 = (const float*)d_in[3];
  const float* b2 = (const float*)d_in[4];
  const float* W3 = (const float*)d_in[5];
  const float* b3 = (const float*)d_in[6];
  float* out = (float*)d_out;
  char* w = (char*)d_ws;
  const size_t MB = 1024 * 1024;

  float* F    = (float*)(w);
  float* v1   = (float*)(w + 9 * MB);
  float* w2v  = (float*)(w + 9 * MB + 131072);
  float* w3v  = (float*)(w + 9 * MB + 262144);
  float* c1   = (float*)(w + 9 * MB + 393216);
  float* c2   = (float*)(w + 9 * MB + 395264);
  float* c3   = (float*)(w + 9 * MB + 397312);
  float* Pst  = (float*)(w + 10 * MB);             // 1 MB fp32
  _Float16* CmTh = (_Float16*)(w + 11 * MB);
  _Float16* SmTh = (_Float16*)(w + 11 * MB + 524288);
  _Float16* Cmh  = (_Float16*)(w + 12 * MB);
  _Float16* Smnh = (_Float16*)(w + 12 * MB + 524288);
  _Float16* M1T  = (_Float16*)(w + 13 * MB);
  _Float16* M2T  = (_Float16*)(w + 13 * MB + 524288);
  _Float16* M3T  = (_Float16*)(w + 14 * MB);
  float* Q2      = (float*)(w + 14 * MB + 524288); // 512 KB fp32
  float* Q3      = (float*)(w + 15 * MB);          // 256 KB fp32
  _Float16* Xh   = (_Float16*)(w + 16 * MB);       // 32 MB
  _Float16* zc   = (_Float16*)(w + 48 * MB);       // 16 MB
  _Float16* zs   = (_Float16*)(w + 64 * MB);       // 16 MB
  _Float16* Pc2h = (_Float16*)(w + 48 * MB);       // over zc (dead)
  _Float16* Ps2h = (_Float16*)(w + 64 * MB);       // over zs (dead)
  _Float16* Pc3h = (_Float16*)(w + 104 * MB);      // 8 MB
  _Float16* Ps3h = (_Float16*)(w + 112 * MB);      // 8 MB, over Zh (dead)
  _Float16* zcT  = (_Float16*)(w + 80 * MB);       // 16 MB
  _Float16* zsT  = (_Float16*)(w + 96 * MB);       // 16 MB
  _Float16* Y2T  = (_Float16*)(w + 80 * MB);       // over zcT (dead)
  _Float16* Y3T  = (_Float16*)(w + 96 * MB);       // 8 MB over zsT (dead)
  _Float16* Zh   = (_Float16*)(w + 112 * MB);      // 16 MB
  _Float16* Y2   = (_Float16*)(w + 128 * MB);      // 16 MB
  _Float16* Y3   = (_Float16*)(w + 144 * MB);      // 8 MB

  // 1. F + tables + rank-1 vectors + c-vectors
  megafill_k<<<2560, 256, 0, stream>>>(F, Cmh, Smnh, CmTh, SmTh, v1, w2v, w3v,
                                       b1, b2, b3, c1, c2, c3);
  // 2. sandwich stage 1
  sgemm_stage1_k<<<28, 256, 0, stream>>>(W1, W2, W3, F, Pst, Q2, Q3);
  // 3. modulation (X fp32 direct + Xh writeback) + sandwich stage 2
  mega3_k<<<1072, 256, 0, stream>>>(X, Xh, zc, zs, F, Pst, Q2, Q3, M1T, M2T, M3T);
  // 4. zc/zs transpose (fused pair)
  transpose2_h_k<<<dim3(512, 8), 256, 0, stream>>>(zc, zcT, 16384, zs, zsT, 16384,
                                                   256, 512);
  // 5. forward shared GEMM (+s_0^2 fixup fused)
  mfma_gemm_k<1><<<dim3(128, 4), 256, 0, stream>>>(Cmh, Smnh, zcT, zsT, Zh, nullptr,
                                                   16384, 0, nullptr, nullptr, 30, 30);
  // 6. coefficient GEMMs Y2+Y3 + branch-1 output (fused trio)
  gemm_trio_k<<<dim3(4, 448), 256, 0, stream>>>(Zh, M2T, M3T, Y2, Y3, Xh, M1T, out,
                                                v1, c1);
  // 7. Y2/Y3 transpose (fused pair)
  transpose2_h_k<<<dim3(384, 8), 256, 0, stream>>>(Y2, Y2T, 16384, Y3, Y3T, 8192,
                                                   256, 512);
  // 8. inverse shared GEMMs (fused branch2+branch3)
  gemm2_pair_k<<<dim3(192, 4), 256, 0, stream>>>(CmTh, SmTh, Y2T, Y3T, Pc2h, Ps2h,
                                                 Pc3h, Ps3h);
  // 9. demodulation, both branches (tables inline)
  demod_pair_k<<<dim3(2, 512, 2), 256, 0, stream>>>(Pc2h, Ps2h, w2v, c2, Pc3h, Ps3h,
                                                    w3v, c3, out);
}

// Round 10
// 585.746 us; speedup vs baseline: 1.0192x; 1.0192x over previous
//
#include <hip/hip_runtime.h>
#include <cstddef>

// ============================================================================
// MultiWaveletTransform — algebraic refactor, all heavy math on MFMA.
// Round 9 resubmit (prior round hit GPUAcquisitionTimeout, never benched):
// R7 base (verified 584.6us) + ONE delta: forward dual GEMM K-merged.
// Zh = Cm.zcT + Smn.zsT == [Cm|Smn].[zcT;zsT] (K=1024, single stream):
// CSh packs cos|-sin per row; transpose writes zc/zs halves into one
// zT[16384][1024]; G1 runs MODE 4 (fp16 + fixup) with KTOT=1024.
// Half the LDS per block -> 2x occupancy, one acc chain.
// ============================================================================

#define PI_D 3.14159265358979323846

typedef _Float16 h8 __attribute__((ext_vector_type(8)));
typedef _Float16 h4 __attribute__((ext_vector_type(4)));
typedef float f4 __attribute__((ext_vector_type(4)));

#define MFMA16(a, b, c) __builtin_amdgcn_mfma_f32_16x16x32_f16(a, b, c, 0, 0, 0)

// ---------------- dispatch 1: F + tables + vectors + c-vecs ----------------
// blocks [0,1024): F        [1024,2048): CS (cos|-sin packed) + CmT/SmT
// [2048,2176): v1/w2/w3     [2176,2560): c1/c2/c3 = F^T b
__global__ __launch_bounds__(256) void megafill_k(
    float* __restrict__ F, _Float16* __restrict__ CSh,
    _Float16* __restrict__ CmTh, _Float16* __restrict__ SmTh,
    float* __restrict__ v1, float* __restrict__ w2, float* __restrict__ w3,
    const float* __restrict__ b1, const float* __restrict__ b2,
    const float* __restrict__ b3, float* __restrict__ c1, float* __restrict__ c2,
    float* __restrict__ c3) {
  const int blk = blockIdx.x;
  const int tid = threadIdx.x;
  if (blk < 1024) {
    int idx = blk * 256 + tid;
    int k = idx >> 9, m = idx & 511;
    int a = (k * (2 * m + 1)) & 2047;
    float ang = (float)(a * (PI_D / 1024.0));
    float s = (k == 0) ? 0.04419417382415922f : 0.0625f;
    F[idx] = s * cosf(ang);
  } else if (blk < 2048) {
    int idx = (blk - 1024) * 256 + tid;
    int t = idx >> 9, v = idx & 511;
    int a = (t * (2 * v + 1)) & 2047;
    float ang = (float)(a * (PI_D / 1024.0));
    float c = cosf(ang), s = sinf(ang);
    CSh[t * 1024 + v] = (_Float16)c;          // cos half (k = 0..511)
    CSh[t * 1024 + 512 + v] = (_Float16)(-s); // -sin half (k = 512..1023)
    CmTh[v * 512 + t] = (_Float16)c;
    SmTh[v * 512 + t] = (_Float16)s;
  } else if (blk < 2176) {
    int n = (blk - 2048) * 256 + tid;
    const double s1 = 0.005524271728019903;
    const double s2 = 0.0078125;
    double th = (2 * n + 1) * (PI_D / 65536.0);
    double c = cos(th), s = sin(th);
    double Dr = 1.0 - c, Di = -s;
    double dd = Dr * Dr + Di * Di;
    double Nr = 1.0, Ni = (n & 1) ? 1.0 : -1.0;
    double vre = (Nr * Dr + Ni * Di) / dd;
    v1[n] = (float)(s2 * vre + (s1 - s2));
    int m64 = (2 * n + 1) & 2047;
    double a64 = m64 * (PI_D / 1024.0);
    double D64r = 1.0 - cos(a64), D64i = -sin(a64);
    double d64 = D64r * D64r + D64i * D64i;
    double Gr = (Nr * D64r + Ni * D64i) / d64;
    double Gi = (Ni * D64r - Nr * D64i) / d64;
    int m32 = (2 * n + 1) & 4095;
    double a32 = m32 * (PI_D / 2048.0);
    double S32nr = 1.0 - cos(a32), S32ni = -sin(a32);
    double S32r = (S32nr * Dr + S32ni * Di) / dd;
    double S32i = (S32ni * Dr - S32nr * Di) / dd;
    w2[n] = (float)(s2 * (S32r * Gr - S32i * Gi) + (s1 - s2));
    int m16 = (2 * n + 1) & 8191;
    double a16 = m16 * (PI_D / 4096.0);
    double S16nr = 1.0 - cos(a16), S16ni = -sin(a16);
    double S16r = (S16nr * Dr + S16ni * Di) / dd;
    double S16i = (S16ni * Dr - S16nr * Di) / dd;
    w3[n] = (float)(s2 * (S16r * Gr - S16i * Gi) + (s1 - s2));
  } else {
    // c_i[l] = sum_m F[m][l] * b_i[m], one wave per (branch,l)
    int gid = (blk - 2176) * 4 + (tid >> 6);
    int lane = tid & 63;
    int branch = gid >> 9;
    int l = gid & 511;
    int K = 512 >> branch;
    const float* b = (branch == 0) ? b1 : (branch == 1) ? b2 : b3;
    float acc = 0.f;
    for (int m = lane; m < K; m += 64) {
      int a = (m * (2 * l + 1)) & 2047;
      float s = (m == 0) ? 0.04419417382415922f : 0.0625f;
      acc += s * cosf((float)(a * (PI_D / 1024.0))) * b[m];
    }
#pragma unroll
    for (int o = 32; o > 0; o >>= 1) acc += __shfl_down(acc, o, 64);
    if (lane == 0) {
      float* c = (branch == 0) ? c1 : (branch == 1) ? c2 : c3;
      c[l] = acc;
    }
  }
}

__global__ void conv_xh_k(const float* __restrict__ X, _Float16* __restrict__ Xh) {
  int i = blockIdx.x * 256 + threadIdx.x;
  float4 v = ((const float4*)X)[i];
  h4 o;
  o[0] = (_Float16)v.x; o[1] = (_Float16)v.y; o[2] = (_Float16)v.z; o[3] = (_Float16)v.w;
  ((h4*)Xh)[i] = o;
}

// ---------------- small MFMA GEMM for precompute (R1 version) ----------------
// C[m][n] = sum_k A'[k][m] * B[k][n]  (B always [K][N] fp32, transpose-staged;
// A: transA=1 -> A[k][m], transA=0 -> A[m][k]).  Out fp32 or f16*scale, ldc=512.
__device__ void sgemm_dev(_Float16* As, _Float16* Bs, int bx, int by,
                          const float* __restrict__ A, int lda, int transA,
                          const float* __restrict__ B, int ldb,
                          float* __restrict__ Cf, _Float16* __restrict__ C16,
                          int K, float scale) {
  const int tid = threadIdx.x;
  const int lane = tid & 63;
  const int wm = (tid >> 6) & 1, wn = tid >> 7;
  const int m0 = by * 128, n0 = bx * 128;
  const int fm = lane & 15, fko = (lane >> 4) * 8;
  f4 acc[4][4] = {};
  for (int k0 = 0; k0 < K; k0 += 32) {
    if (transA) {
#pragma unroll
      for (int i = 0; i < 4; i++) {
        int idx4 = tid + i * 256;
        int kk = idx4 & 31, mc = (idx4 >> 5) * 4;
        float4 v = *(const float4*)&A[(size_t)(k0 + kk) * lda + m0 + mc];
        As[(mc + 0) * 40 + kk] = (_Float16)v.x;
        As[(mc + 1) * 40 + kk] = (_Float16)v.y;
        As[(mc + 2) * 40 + kk] = (_Float16)v.z;
        As[(mc + 3) * 40 + kk] = (_Float16)v.w;
      }
    } else {
#pragma unroll
      for (int i = 0; i < 4; i++) {
        int idx4 = tid + i * 256;
        int mm = idx4 >> 3, kc = (idx4 & 7) * 4;
        float4 v = *(const float4*)&A[(size_t)(m0 + mm) * lda + k0 + kc];
        h4 o;
        o[0] = (_Float16)v.x; o[1] = (_Float16)v.y; o[2] = (_Float16)v.z; o[3] = (_Float16)v.w;
        *(h4*)&As[mm * 40 + kc] = o;
      }
    }
#pragma unroll
    for (int i = 0; i < 4; i++) {
      int idx4 = tid + i * 256;
      int kk = idx4 & 31, nc = (idx4 >> 5) * 4;
      float4 v = *(const float4*)&B[(size_t)(k0 + kk) * ldb + n0 + nc];
      Bs[(nc + 0) * 40 + kk] = (_Float16)v.x;
      Bs[(nc + 1) * 40 + kk] = (_Float16)v.y;
      Bs[(nc + 2) * 40 + kk] = (_Float16)v.z;
      Bs[(nc + 3) * 40 + kk] = (_Float16)v.w;
    }
    __syncthreads();
    h8 af[4], bf[4];
#pragma unroll
    for (int i = 0; i < 4; i++) af[i] = *(const h8*)&As[(wm * 64 + i * 16 + fm) * 40 + fko];
#pragma unroll
    for (int j = 0; j < 4; j++) bf[j] = *(const h8*)&Bs[(wn * 64 + j * 16 + fm) * 40 + fko];
#pragma unroll
    for (int i = 0; i < 4; i++)
#pragma unroll
      for (int j = 0; j < 4; j++) acc[i][j] = MFMA16(af[i], bf[j], acc[i][j]);
    __syncthreads();
  }
  const int er = (lane >> 4) * 4, ec = lane & 15;
#pragma unroll
  for (int i = 0; i < 4; i++) {
    int gr0 = m0 + wm * 64 + i * 16 + er;
#pragma unroll
    for (int j = 0; j < 4; j++) {
      int gc = n0 + wn * 64 + j * 16 + ec;
#pragma unroll
      for (int r = 0; r < 4; r++) {
        size_t off = (size_t)(gr0 + r) * 512 + gc;
        if (C16) C16[off] = (_Float16)(acc[i][j][r] * scale);
        else Cf[off] = acc[i][j][r];
      }
    }
  }
}

// stage 1: Pst = W1^T F (16 blk) | Q2 = W2 F1 (8 blk) | Q3 = W3 F2 (4 blk)
__global__ __launch_bounds__(256) void sgemm_stage1_k(
    const float* __restrict__ W1, const float* __restrict__ W2,
    const float* __restrict__ W3, const float* __restrict__ F,
    float* __restrict__ Pst, float* __restrict__ Q2, float* __restrict__ Q3) {
  __shared__ _Float16 As[128 * 40];
  __shared__ _Float16 Bs[128 * 40];
  int id = blockIdx.x;
  if (id < 16) {
    sgemm_dev(As, Bs, id & 3, id >> 2, W1, 512, 1, F, 512, Pst, nullptr, 512, 1.f);
  } else if (id < 24) {
    int j = id - 16;
    sgemm_dev(As, Bs, j & 3, j >> 2, W2, 256, 0, F, 512, Q2, nullptr, 256, 1.f);
  } else {
    int j = id - 24;
    sgemm_dev(As, Bs, j & 3, j >> 2, W3, 128, 0, F, 512, Q3, nullptr, 128, 1.f);
  }
}

// stage 2: M1T = Pst^T F | M2T = F^T Q2 | M3T = F^T Q3   (16 blocks each)
__global__ __launch_bounds__(256) void sgemm_stage2_k(
    const float* __restrict__ F, const float* __restrict__ Pst,
    const float* __restrict__ Q2, const float* __restrict__ Q3,
    _Float16* __restrict__ M1T, _Float16* __restrict__ M2T,
    _Float16* __restrict__ M3T) {
  __shared__ _Float16 As[128 * 40];
  __shared__ _Float16 Bs[128 * 40];
  int id = blockIdx.x;
  if (id < 16) {
    sgemm_dev(As, Bs, id & 3, id >> 2, Pst, 512, 1, F, 512, nullptr, M1T, 512, 1.f);
  } else if (id < 32) {
    int j = id - 16;
    sgemm_dev(As, Bs, j & 3, j >> 2, F, 512, 1, Q2, 512, nullptr, M2T, 256, 0.0078125f);
  } else {
    int j = id - 32;
    sgemm_dev(As, Bs, j & 3, j >> 2, F, 512, 1, Q3, 512, nullptr, M3T, 128, 0.0078125f);
  }
}

// ---------------- fp16 tiled transpose, two jobs per launch ----------------
// out[x*R + y(+off)] = in[y*C + x]; R is the OUT row stride.
__global__ __launch_bounds__(256) void transpose2_h_k(
    const _Float16* __restrict__ in0, _Float16* __restrict__ out0, int C0,
    const _Float16* __restrict__ in1, _Float16* __restrict__ out1, int C1,
    int xsplit, int R) {
  __shared__ _Float16 t[64][66];
  const _Float16* in;
  _Float16* out;
  int C, bx;
  if ((int)blockIdx.x < xsplit) { in = in0; out = out0; C = C0; bx = blockIdx.x; }
  else { in = in1; out = out1; C = C1; bx = blockIdx.x - xsplit; }
  int tid = threadIdx.x;
  int bxo = bx * 64;
  int by = blockIdx.y * 64;
  int cx = (tid & 15) * 4;
  int ry = tid >> 4;
#pragma unroll
  for (int p = 0; p < 4; p++) {
    int r = ry + p * 16;
    h4 v = *(const h4*)&in[(size_t)(by + r) * C + bxo + cx];
    t[r][cx + 0] = v[0]; t[r][cx + 1] = v[1]; t[r][cx + 2] = v[2]; t[r][cx + 3] = v[3];
  }
  __syncthreads();
#pragma unroll
  for (int p = 0; p < 4; p++) {
    int r2 = ry + p * 16;
    h4 v;
    v[0] = t[cx + 0][r2]; v[1] = t[cx + 1][r2]; v[2] = t[cx + 2][r2]; v[3] = t[cx + 3][r2];
    *(h4*)&out[(size_t)(bxo + r2) * R + by + cx] = v;
  }
}

// ---------------- main f16 MFMA GEMM (device fn, async16 staging) -----------
// MODE: 0 = fp16 out; 2 = dual-A dual-out fp16; 3 = fp32 out + rank-1;
//       4 = fp16 out + s_0^2 fixup (single stream).   KTOT = contraction len.
__device__ __forceinline__ void async16(const _Float16* g, _Float16* l) {
  __builtin_amdgcn_global_load_lds((const __attribute__((address_space(1))) void*)g,
                                   (__attribute__((address_space(3))) void*)l, 16, 0, 0);
}

template <int MODE, int KTOT>
__device__ void gemm_dev(_Float16* As, _Float16* Bs, int bx, int by,
                         const _Float16* __restrict__ A1, const _Float16* __restrict__ A2,
                         const _Float16* __restrict__ B1, const _Float16* __restrict__ B2,
                         void* __restrict__ C1, void* __restrict__ C2, int ldc, int coff,
                         const float* __restrict__ u, const float* __restrict__ wvec,
                         int sb, int tb) {
  constexpr bool DA = (MODE == 2);
  const int tid = threadIdx.x;
  const int lane = tid & 63;
  const int wm = (tid >> 6) & 1, wn = tid >> 7;
  const int m0 = by * 128, n0 = bx * 128;
  const int srow = tid >> 2, scol = (tid & 3) * 8;
  const int mask = (1 << sb) - 1;
  f4 acc[4][4] = {};
  f4 acc2[4][4] = {};
  const int fm = lane & 15, fko = (lane >> 4) * 8;
  for (int k0 = 0; k0 < KTOT; k0 += 32) {
#pragma unroll
    for (int i = 0; i < 2; i++) {
      int r = m0 + i * 64 + srow;
      int pr = ((r >> sb) << tb) | (r & mask);
      async16(A1 + (size_t)pr * KTOT + k0 + scol, &As[i * 2048 + tid * 8]);
      if constexpr (DA)
        async16(A2 + (size_t)pr * KTOT + k0 + scol, &As[4096 + i * 2048 + tid * 8]);
      int rb = n0 + i * 64 + srow;
      async16(B1 + (size_t)rb * KTOT + k0 + scol, &Bs[i * 2048 + tid * 8]);
    }
    __syncthreads();
    h8 af[4], bf[4], af2[4];
#pragma unroll
    for (int i = 0; i < 4; i++) {
      int ro = (wm * 64 + i * 16 + fm) * 32 + fko;
      af[i] = *(const h8*)&As[ro];
      if constexpr (DA) af2[i] = *(const h8*)&As[4096 + ro];
    }
#pragma unroll
    for (int j = 0; j < 4; j++) {
      int co = (wn * 64 + j * 16 + fm) * 32 + fko;
      bf[j] = *(const h8*)&Bs[co];
    }
#pragma unroll
    for (int i = 0; i < 4; i++)
#pragma unroll
      for (int j = 0; j < 4; j++) {
        acc[i][j] = MFMA16(af[i], bf[j], acc[i][j]);
        if constexpr (MODE == 2) acc2[i][j] = MFMA16(af2[i], bf[j], acc2[i][j]);
      }
    __syncthreads();
  }
  const int er = (lane >> 4) * 4, ec = lane & 15;
#pragma unroll
  for (int i = 0; i < 4; i++) {
    int gr0 = m0 + wm * 64 + i * 16 + er;
#pragma unroll
    for (int j = 0; j < 4; j++) {
      int gc = n0 + wn * 64 + j * 16 + ec;
#pragma unroll
      for (int r = 0; r < 4; r++) {
        size_t off = (size_t)(gr0 + r) * ldc + coff + gc;
        if constexpr (MODE == 3) {
          ((float*)C1)[off] = acc[i][j][r] + u[gr0 + r] * wvec[gc];
        } else if constexpr (MODE == 2) {
          ((_Float16*)C1)[off] = (_Float16)acc[i][j][r];
          ((_Float16*)C2)[off] = (_Float16)acc2[i][j][r];
        } else if constexpr (MODE == 4) {
          float v = acc[i][j][r];
          if ((gr0 + r) == 0 && gc < 512) v *= 0.5f;  // fused s_0^2 fixup (t=0,j=0)
          ((_Float16*)C1)[off] = (_Float16)v;
        } else {
          ((_Float16*)C1)[off] = (_Float16)acc[i][j][r];
        }
      }
    }
  }
}

template <int MODE, int KTOT>
__global__ __launch_bounds__(256) void mfma_gemm_k(
    const _Float16* __restrict__ A1, const _Float16* __restrict__ A2,
    const _Float16* __restrict__ B1, const _Float16* __restrict__ B2,
    void* __restrict__ C1, void* __restrict__ C2, int ldc, int coff,
    const float* __restrict__ u, const float* __restrict__ wvec, int sb, int tb) {
  __shared__ __align__(16) _Float16 As[(MODE == 2 ? 2 : 1) * 4096];
  __shared__ __align__(16) _Float16 Bs[4096];
  gemm_dev<MODE, KTOT>(As, Bs, blockIdx.x, blockIdx.y, A1, A2, B1, B2, C1, C2, ldc,
                       coff, u, wvec, sb, tb);
}

// Y2 = Zh M2T (by<128) | Y3 = Zh[j<16] M3T (by in [128,192))
// | out1 = X M1 + v1 c1^T (by >= 192)
__global__ __launch_bounds__(256) void gemm_trio_k(
    const _Float16* __restrict__ Zh, const _Float16* __restrict__ M2T,
    const _Float16* __restrict__ M3T, _Float16* __restrict__ Y2,
    _Float16* __restrict__ Y3, const _Float16* __restrict__ Xh,
    const _Float16* __restrict__ M1T, float* __restrict__ out,
    const float* __restrict__ v1, const float* __restrict__ c1) {
  __shared__ __align__(16) _Float16 As[4096];
  __shared__ __align__(16) _Float16 Bs[4096];
  int by = blockIdx.y;
  if (by < 128)
    gemm_dev<0, 512>(As, Bs, blockIdx.x, by, Zh, nullptr, M2T, nullptr, Y2, nullptr,
                     512, 0, nullptr, nullptr, 30, 30);
  else if (by < 192)
    gemm_dev<0, 512>(As, Bs, blockIdx.x, by - 128, Zh, nullptr, M3T, nullptr, Y3,
                     nullptr, 512, 0, nullptr, nullptr, 4, 5);
  else
    gemm_dev<3, 512>(As, Bs, blockIdx.x, by - 192, Xh, nullptr, M1T, nullptr, out,
                     nullptr, 1536, 0, v1, c1, 30, 30);
}

// Pc2/Ps2 = CmT/SmT . Y2T (bx<128, ldc 16384) | Pc3/Ps3 = . Y3T (bx>=128, ldc 8192)
__global__ __launch_bounds__(256) void gemm2_pair_k(
    const _Float16* __restrict__ CmTh, const _Float16* __restrict__ SmTh,
    const _Float16* __restrict__ Y2T, const _Float16* __restrict__ Y3T,
    _Float16* __restrict__ Pc2, _Float16* __restrict__ Ps2,
    _Float16* __restrict__ Pc3, _Float16* __restrict__ Ps3) {
  __shared__ __align__(16) _Float16 As[2 * 4096];
  __shared__ __align__(16) _Float16 Bs[4096];
  if ((int)blockIdx.x < 128)
    gemm_dev<2, 512>(As, Bs, blockIdx.x, blockIdx.y, CmTh, SmTh, Y2T, nullptr, Pc2,
                     Ps2, 16384, 0, nullptr, nullptr, 30, 30);
  else
    gemm_dev<2, 512>(As, Bs, blockIdx.x - 128, blockIdx.y, CmTh, SmTh, Y3T, nullptr,
                     Pc3, Ps3, 8192, 0, nullptr, nullptr, 30, 30);
}

// ---------------- MFMA modulation (tables inline) ----------------
__global__ __launch_bounds__(256) void modmfma_k(
    const _Float16* __restrict__ Xh, _Float16* __restrict__ zc,
    _Float16* __restrict__ zs) {
  __shared__ _Float16 Bs[256 * 72];
  __shared__ _Float16 Ac[32 * 72];
  __shared__ _Float16 As[32 * 72];
  const int tid = threadIdx.x;
  const int lane = tid & 63;
  const int wid = tid >> 6;
  const int vp = blockIdx.y;
  const int l0 = blockIdx.x * 256;
  const float sc = 0.0078125f;
  {  // stage X transposed: lane -> k-row
    int r = lane;
    int u = r & 31;
    int n = (r < 32) ? ((u << 10) + vp) : ((u << 10) + 1023 - vp);
    const _Float16* src = Xh + (size_t)n * 512 + l0 + wid * 64;
#pragma unroll
    for (int i = 0; i < 8; i++) {
      h8 v = *(const h8*)(src + i * 8);
      int lb = wid * 64 + i * 8;
#pragma unroll
      for (int e = 0; e < 8; e++) Bs[(lb + e) * 72 + r] = v[e];
    }
  }
  for (int idx = tid; idx < 2048; idx += 256) {  // tables, trig inline
    int kk = idx & 63, j = idx >> 6;
    int u = kk & 31;
    int n = (kk < 32) ? ((u << 10) + vp) : ((u << 10) + 1023 - vp);
    int a = (j * (2 * n + 1)) & 131071;
    float sv, cv;
    __sincosf((float)(a * (PI_D / 65536.0)), &sv, &cv);
    Ac[j * 72 + kk] = (_Float16)(cv * sc);
    As[j * 72 + kk] = (_Float16)(((kk < 32) ? sv : -sv) * sc);
  }
  __syncthreads();
  const int fm = lane & 15, fko = (lane >> 4) * 8;
  f4 accc[2][4] = {};
  f4 accs[2][4] = {};
#pragma unroll
  for (int ks = 0; ks < 2; ks++) {
    int ko = ks * 32 + fko;
    h8 afc[2], afs[2], bf[4];
#pragma unroll
    for (int i = 0; i < 2; i++) {
      afc[i] = *(const h8*)&Ac[(i * 16 + fm) * 72 + ko];
      afs[i] = *(const h8*)&As[(i * 16 + fm) * 72 + ko];
    }
#pragma unroll
    for (int j = 0; j < 4; j++)
      bf[j] = *(const h8*)&Bs[(wid * 64 + j * 16 + fm) * 72 + ko];
#pragma unroll
    for (int i = 0; i < 2; i++)
#pragma unroll
      for (int j = 0; j < 4; j++) {
        accc[i][j] = MFMA16(afc[i], bf[j], accc[i][j]);
        accs[i][j] = MFMA16(afs[i], bf[j], accs[i][j]);
      }
  }
  const int er = (lane >> 4) * 4, ec = lane & 15;
#pragma unroll
  for (int i = 0; i < 2; i++)
#pragma unroll
    for (int j = 0; j < 4; j++)
#pragma unroll
      for (int r = 0; r < 4; r++) {
        int row = i * 16 + er + r;
        int col = l0 + wid * 64 + j * 16 + ec;
        size_t off = (size_t)vp * 16384 + row * 512 + col;
        zc[off] = (_Float16)accc[i][j][r];
        zs[off] = (_Float16)accs[i][j][r];
      }
}

// ---------------- MFMA demodulation (tables inline, both branches fused) ----
template <int JC>
__device__ void demod_dev(char* smemraw, const _Float16* __restrict__ Pc,
                          const _Float16* __restrict__ Ps,
                          const float* __restrict__ wv, const float* __restrict__ cw,
                          float* __restrict__ out, int coff) {
  constexpr int K2 = 2 * JC;
  constexpr int ST = K2 + 8;
  _Float16* Bs = (_Float16*)smemraw;                          // 256*ST
  _Float16* At = (_Float16*)(smemraw + (size_t)256 * ST * 2); // 64*ST
  const int tid = threadIdx.x;
  const int lane = tid & 63;
  const int wid = tid >> 6;
  const int vp = blockIdx.y;
  const int l0 = blockIdx.x * 256;
  {  // stage P transposed
    constexpr int CPL = 64 / K2;
    int r = lane & (K2 - 1);
    int chunk = wid * CPL + (CPL == 1 ? 0 : (lane >> 5));
    int lb = chunk * K2;
    const _Float16* src = (r < JC ? Pc + (size_t)vp * (JC * 512) + r * 512
                                  : Ps + (size_t)vp * (JC * 512) + (r - JC) * 512) +
                          l0 + lb;
#pragma unroll
    for (int i = 0; i < K2 / 8; i++) {
      h8 v = *(const h8*)(src + i * 8);
#pragma unroll
      for (int e = 0; e < 8; e++) Bs[(lb + i * 8 + e) * ST + r] = v[e];
    }
  }
  for (int idx = tid; idx < 64 * K2; idx += 256) {  // tables, trig inline
    int kk = idx & (K2 - 1), m = idx / K2;
    int ab = m >> 5, u = m & 31;
    int n = ab ? ((u << 10) + 1023 - vp) : ((u << 10) + vp);
    int twon = 2 * n + 1;
    float val;
    if (kk < JC) {
      int a = (kk * twon) & 131071;
      val = cosf((float)(a * (PI_D / 65536.0)));
    } else {
      int a = ((kk - JC) * twon) & 131071;
      float sv = sinf((float)(a * (PI_D / 65536.0)));
      val = ab ? sv : -sv;
    }
    At[m * ST + kk] = (_Float16)val;
  }
  __syncthreads();
  const int fm = lane & 15, fko = (lane >> 4) * 8;
  f4 acc[4][4] = {};
#pragma unroll
  for (int ks = 0; ks < K2 / 32; ks++) {
    int ko = ks * 32 + fko;
    h8 af[4], bf[4];
#pragma unroll
    for (int i = 0; i < 4; i++) af[i] = *(const h8*)&At[(i * 16 + fm) * ST + ko];
#pragma unroll
    for (int j = 0; j < 4; j++) bf[j] = *(const h8*)&Bs[(wid * 64 + j * 16 + fm) * ST + ko];
#pragma unroll
    for (int i = 0; i < 4; i++)
#pragma unroll
      for (int j = 0; j < 4; j++) acc[i][j] = MFMA16(af[i], bf[j], acc[i][j]);
  }
  const int er = (lane >> 4) * 4, ec = lane & 15;
#pragma unroll
  for (int i = 0; i < 4; i++)
#pragma unroll
    for (int j = 0; j < 4; j++) {
      int col = l0 + wid * 64 + j * 16 + ec;
      float cl = cw[col];
#pragma unroll
      for (int r = 0; r < 4; r++) {
        int m = i * 16 + er + r;
        int ab = m >> 5, u = m & 31;
        int n = ab ? ((u << 10) + 1023 - vp) : ((u << 10) + vp);
        out[(size_t)n * 1536 + coff + col] = acc[i][j][r] + wv[n] * cl;
      }
    }
}

__global__ __launch_bounds__(256) void demod_pair_k(
    const _Float16* __restrict__ Pc2, const _Float16* __restrict__ Ps2,
    const float* __restrict__ w2v, const float* __restrict__ c2,
    const _Float16* __restrict__ Pc3, const _Float16* __restrict__ Ps3,
    const float* __restrict__ w3v, const float* __restrict__ c3,
    float* __restrict__ out) {
  __shared__ __align__(16) char smem[256 * 72 * 2 + 64 * 72 * 2];  // 46080 B
  if (blockIdx.z == 0)
    demod_dev<32>(smem, Pc2, Ps2, w2v, c2, out, 512);
  else
    demod_dev<16>(smem, Pc3, Ps3, w3v, c3, out, 1024);
}

// ---------------- launch ----------------
extern "C" void kernel_launch(void* const* d_in, const int* in_sizes, int n_in,
                              void* d_out, int out_size, void* d_ws, size_t ws_size,
                              hipStream_t stream) {
  const float* X  = (const float*)d_in[0];
  const float* W1 = (const float*)d_in[1];
  const float* b1 = (const float*)d_in[2];
  const float* W2 = (const float*)d_in[3];
  const float* b2 = (const float*)d_in[4];
  const float* W3 = (const float*)d_in[5];
  const float* b3 = (const float*)d_in[6];
  float* out = (float*)d_out;
  char* w = (char*)d_ws;
  const size_t MB = 1024 * 1024;

  float* F    = (float*)(w);
  float* v1   = (float*)(w + 9 * MB);
  float* w2v  = (float*)(w + 9 * MB + 131072);
  float* w3v  = (float*)(w + 9 * MB + 262144);
  float* c1   = (float*)(w + 9 * MB + 393216);
  float* c2   = (float*)(w + 9 * MB + 395264);
  float* c3   = (float*)(w + 9 * MB + 397312);
  float* Pst  = (float*)(w + 10 * MB);             // 1 MB fp32
  _Float16* CmTh = (_Float16*)(w + 11 * MB);
  _Float16* SmTh = (_Float16*)(w + 11 * MB + 524288);
  _Float16* CSh  = (_Float16*)(w + 12 * MB);       // [512][1024] cos|-sin, 1 MB
  _Float16* M1T  = (_Float16*)(w + 13 * MB);
  _Float16* M2T  = (_Float16*)(w + 13 * MB + 524288);
  _Float16* M3T  = (_Float16*)(w + 14 * MB);
  float* Q2      = (float*)(w + 14 * MB + 524288); // 512 KB fp32
  float* Q3      = (float*)(w + 15 * MB);          // 256 KB fp32
  _Float16* Xh   = (_Float16*)(w + 16 * MB);       // 32 MB
  _Float16* zc   = (_Float16*)(w + 48 * MB);       // 16 MB
  _Float16* zs   = (_Float16*)(w + 64 * MB);       // 16 MB
  _Float16* Pc2h = (_Float16*)(w + 48 * MB);       // over zc (dead)
  _Float16* Ps2h = (_Float16*)(w + 64 * MB);       // over zs (dead)
  _Float16* Pc3h = (_Float16*)(w + 104 * MB);      // 8 MB
  _Float16* Ps3h = (_Float16*)(w + 112 * MB);      // 8 MB, over Zh (dead)
  _Float16* zT   = (_Float16*)(w + 80 * MB);       // [16384][1024], 32 MB (80-112)
  _Float16* Y2T  = (_Float16*)(w + 80 * MB);       // over zT (dead)
  _Float16* Y3T  = (_Float16*)(w + 96 * MB);       // 8 MB over zT (dead)
  _Float16* Zh   = (_Float16*)(w + 112 * MB);      // 16 MB
  _Float16* Y2   = (_Float16*)(w + 128 * MB);      // 16 MB
  _Float16* Y3   = (_Float16*)(w + 144 * MB);      // 8 MB

  // 1. F + tables (CS packed) + rank-1 vectors + c-vectors
  megafill_k<<<2560, 256, 0, stream>>>(F, CSh, CmTh, SmTh, v1, w2v, w3v,
                                       b1, b2, b3, c1, c2, c3);
  // 2-3. M-matrix sandwich GEMMs
  sgemm_stage1_k<<<28, 256, 0, stream>>>(W1, W2, W3, F, Pst, Q2, Q3);
  sgemm_stage2_k<<<48, 256, 0, stream>>>(F, Pst, Q2, Q3, M1T, M2T, M3T);
  // 4. X -> fp16
  conv_xh_k<<<16384, 256, 0, stream>>>(X, Xh);
  // 5. modulation (tables inline)
  modmfma_k<<<dim3(2, 512), 256, 0, stream>>>(Xh, zc, zs);
  // 6. zc/zs transpose into stacked zT[16384][1024] (zc -> cols 0:512,
  //    zs -> cols 512:1024) — same write pattern, row stride 1024
  transpose2_h_k<<<dim3(512, 8), 256, 0, stream>>>(zc, zT, 16384, zs, zT + 512,
                                                   16384, 256, 1024);
  // 7. forward GEMM, K=1024 single stream: Zh = [Cm|Smn].[zcT;zsT] (+fixup)
  mfma_gemm_k<4, 1024><<<dim3(128, 4), 256, 0, stream>>>(
      CSh, nullptr, zT, nullptr, Zh, nullptr, 16384, 0, nullptr, nullptr, 30, 30);
  // 8. coefficient GEMMs Y2+Y3 + branch-1 output (fused trio)
  gemm_trio_k<<<dim3(4, 448), 256, 0, stream>>>(Zh, M2T, M3T, Y2, Y3, Xh, M1T, out,
                                                v1, c1);
  // 9. Y2/Y3 transpose (fused pair)
  transpose2_h_k<<<dim3(384, 8), 256, 0, stream>>>(Y2, Y2T, 16384, Y3, Y3T, 8192,
                                                   256, 512);
  // 10. inverse shared GEMMs (fused branch2+branch3)
  gemm2_pair_k<<<dim3(192, 4), 256, 0, stream>>>(CmTh, SmTh, Y2T, Y3T, Pc2h, Ps2h,
                                                 Pc3h, Ps3h);
  // 11. demodulation, both branches (tables inline)
  demod_pair_k<<<dim3(2, 512, 2), 256, 0, stream>>>(Pc2h, Ps2h, w2v, c2, Pc3h, Ps3h,
                                                    w3v, c3, out);
}

// Round 11
// 577.500 us; speedup vs baseline: 1.0337x; 1.0143x over previous
//
#include <hip/hip_runtime.h>
#include <cstddef>

// ============================================================================
// MultiWaveletTransform — algebraic refactor, all heavy math on MFMA.
// Round 11: R10 base (585.7us verified; K-merged G1 kept — neutral but
// simpler) + ONE delta: branch-1 GEMM (out1 = Xh.M1T, independent of G1)
// moved from the trio dispatch into the G1 dispatch. G1 alone is 512 blocks
// = 2 blocks/CU (underfilled); merged 1536-block grid fills the CUs
// (m114 co-scheduling). Trio -> duo (Y2+Y3, 768 blocks).
// ============================================================================

#define PI_D 3.14159265358979323846

typedef _Float16 h8 __attribute__((ext_vector_type(8)));
typedef _Float16 h4 __attribute__((ext_vector_type(4)));
typedef float f4 __attribute__((ext_vector_type(4)));

#define MFMA16(a, b, c) __builtin_amdgcn_mfma_f32_16x16x32_f16(a, b, c, 0, 0, 0)

// ---------------- dispatch 1: F + tables + vectors + c-vecs ----------------
// blocks [0,1024): F        [1024,2048): CS (cos|-sin packed) + CmT/SmT
// [2048,2176): v1/w2/w3     [2176,2560): c1/c2/c3 = F^T b
__global__ __launch_bounds__(256) void megafill_k(
    float* __restrict__ F, _Float16* __restrict__ CSh,
    _Float16* __restrict__ CmTh, _Float16* __restrict__ SmTh,
    float* __restrict__ v1, float* __restrict__ w2, float* __restrict__ w3,
    const float* __restrict__ b1, const float* __restrict__ b2,
    const float* __restrict__ b3, float* __restrict__ c1, float* __restrict__ c2,
    float* __restrict__ c3) {
  const int blk = blockIdx.x;
  const int tid = threadIdx.x;
  if (blk < 1024) {
    int idx = blk * 256 + tid;
    int k = idx >> 9, m = idx & 511;
    int a = (k * (2 * m + 1)) & 2047;
    float ang = (float)(a * (PI_D / 1024.0));
    float s = (k == 0) ? 0.04419417382415922f : 0.0625f;
    F[idx] = s * cosf(ang);
  } else if (blk < 2048) {
    int idx = (blk - 1024) * 256 + tid;
    int t = idx >> 9, v = idx & 511;
    int a = (t * (2 * v + 1)) & 2047;
    float ang = (float)(a * (PI_D / 1024.0));
    float c = cosf(ang), s = sinf(ang);
    CSh[t * 1024 + v] = (_Float16)c;          // cos half (k = 0..511)
    CSh[t * 1024 + 512 + v] = (_Float16)(-s); // -sin half (k = 512..1023)
    CmTh[v * 512 + t] = (_Float16)c;
    SmTh[v * 512 + t] = (_Float16)s;
  } else if (blk < 2176) {
    int n = (blk - 2048) * 256 + tid;
    const double s1 = 0.005524271728019903;
    const double s2 = 0.0078125;
    double th = (2 * n + 1) * (PI_D / 65536.0);
    double c = cos(th), s = sin(th);
    double Dr = 1.0 - c, Di = -s;
    double dd = Dr * Dr + Di * Di;
    double Nr = 1.0, Ni = (n & 1) ? 1.0 : -1.0;
    double vre = (Nr * Dr + Ni * Di) / dd;
    v1[n] = (float)(s2 * vre + (s1 - s2));
    int m64 = (2 * n + 1) & 2047;
    double a64 = m64 * (PI_D / 1024.0);
    double D64r = 1.0 - cos(a64), D64i = -sin(a64);
    double d64 = D64r * D64r + D64i * D64i;
    double Gr = (Nr * D64r + Ni * D64i) / d64;
    double Gi = (Ni * D64r - Nr * D64i) / d64;
    int m32 = (2 * n + 1) & 4095;
    double a32 = m32 * (PI_D / 2048.0);
    double S32nr = 1.0 - cos(a32), S32ni = -sin(a32);
    double S32r = (S32nr * Dr + S32ni * Di) / dd;
    double S32i = (S32ni * Dr - S32nr * Di) / dd;
    w2[n] = (float)(s2 * (S32r * Gr - S32i * Gi) + (s1 - s2));
    int m16 = (2 * n + 1) & 8191;
    double a16 = m16 * (PI_D / 4096.0);
    double S16nr = 1.0 - cos(a16), S16ni = -sin(a16);
    double S16r = (S16nr * Dr + S16ni * Di) / dd;
    double S16i = (S16ni * Dr - S16nr * Di) / dd;
    w3[n] = (float)(s2 * (S16r * Gr - S16i * Gi) + (s1 - s2));
  } else {
    // c_i[l] = sum_m F[m][l] * b_i[m], one wave per (branch,l)
    int gid = (blk - 2176) * 4 + (tid >> 6);
    int lane = tid & 63;
    int branch = gid >> 9;
    int l = gid & 511;
    int K = 512 >> branch;
    const float* b = (branch == 0) ? b1 : (branch == 1) ? b2 : b3;
    float acc = 0.f;
    for (int m = lane; m < K; m += 64) {
      int a = (m * (2 * l + 1)) & 2047;
      float s = (m == 0) ? 0.04419417382415922f : 0.0625f;
      acc += s * cosf((float)(a * (PI_D / 1024.0))) * b[m];
    }
#pragma unroll
    for (int o = 32; o > 0; o >>= 1) acc += __shfl_down(acc, o, 64);
    if (lane == 0) {
      float* c = (branch == 0) ? c1 : (branch == 1) ? c2 : c3;
      c[l] = acc;
    }
  }
}

__global__ void conv_xh_k(const float* __restrict__ X, _Float16* __restrict__ Xh) {
  int i = blockIdx.x * 256 + threadIdx.x;
  float4 v = ((const float4*)X)[i];
  h4 o;
  o[0] = (_Float16)v.x; o[1] = (_Float16)v.y; o[2] = (_Float16)v.z; o[3] = (_Float16)v.w;
  ((h4*)Xh)[i] = o;
}

// ---------------- small MFMA GEMM for precompute (device fn) ----------------
// C[m][n] = sum_k A'[k][m] * B[k][n]  (B always [K][N] fp32, transpose-staged;
// A: transA=1 -> A[k][m], transA=0 -> A[m][k]).  Out fp32 or f16*scale, ldc=512.
__device__ void sgemm_dev(_Float16* As, _Float16* Bs, int bx, int by,
                          const float* __restrict__ A, int lda, int transA,
                          const float* __restrict__ B, int ldb,
                          float* __restrict__ Cf, _Float16* __restrict__ C16,
                          int K, float scale) {
  const int tid = threadIdx.x;
  const int lane = tid & 63;
  const int wm = (tid >> 6) & 1, wn = tid >> 7;
  const int m0 = by * 128, n0 = bx * 128;
  const int fm = lane & 15, fko = (lane >> 4) * 8;
  f4 acc[4][4] = {};
  for (int k0 = 0; k0 < K; k0 += 32) {
    if (transA) {
#pragma unroll
      for (int i = 0; i < 4; i++) {
        int idx4 = tid + i * 256;
        int kk = idx4 & 31, mc = (idx4 >> 5) * 4;
        float4 v = *(const float4*)&A[(size_t)(k0 + kk) * lda + m0 + mc];
        As[(mc + 0) * 40 + kk] = (_Float16)v.x;
        As[(mc + 1) * 40 + kk] = (_Float16)v.y;
        As[(mc + 2) * 40 + kk] = (_Float16)v.z;
        As[(mc + 3) * 40 + kk] = (_Float16)v.w;
      }
    } else {
#pragma unroll
      for (int i = 0; i < 4; i++) {
        int idx4 = tid + i * 256;
        int mm = idx4 >> 3, kc = (idx4 & 7) * 4;
        float4 v = *(const float4*)&A[(size_t)(m0 + mm) * lda + k0 + kc];
        h4 o;
        o[0] = (_Float16)v.x; o[1] = (_Float16)v.y; o[2] = (_Float16)v.z; o[3] = (_Float16)v.w;
        *(h4*)&As[mm * 40 + kc] = o;
      }
    }
#pragma unroll
    for (int i = 0; i < 4; i++) {
      int idx4 = tid + i * 256;
      int kk = idx4 & 31, nc = (idx4 >> 5) * 4;
      float4 v = *(const float4*)&B[(size_t)(k0 + kk) * ldb + n0 + nc];
      Bs[(nc + 0) * 40 + kk] = (_Float16)v.x;
      Bs[(nc + 1) * 40 + kk] = (_Float16)v.y;
      Bs[(nc + 2) * 40 + kk] = (_Float16)v.z;
      Bs[(nc + 3) * 40 + kk] = (_Float16)v.w;
    }
    __syncthreads();
    h8 af[4], bf[4];
#pragma unroll
    for (int i = 0; i < 4; i++) af[i] = *(const h8*)&As[(wm * 64 + i * 16 + fm) * 40 + fko];
#pragma unroll
    for (int j = 0; j < 4; j++) bf[j] = *(const h8*)&Bs[(wn * 64 + j * 16 + fm) * 40 + fko];
#pragma unroll
    for (int i = 0; i < 4; i++)
#pragma unroll
      for (int j = 0; j < 4; j++) acc[i][j] = MFMA16(af[i], bf[j], acc[i][j]);
    __syncthreads();
  }
  const int er = (lane >> 4) * 4, ec = lane & 15;
#pragma unroll
  for (int i = 0; i < 4; i++) {
    int gr0 = m0 + wm * 64 + i * 16 + er;
#pragma unroll
    for (int j = 0; j < 4; j++) {
      int gc = n0 + wn * 64 + j * 16 + ec;
#pragma unroll
      for (int r = 0; r < 4; r++) {
        size_t off = (size_t)(gr0 + r) * 512 + gc;
        if (C16) C16[off] = (_Float16)(acc[i][j][r] * scale);
        else Cf[off] = acc[i][j][r];
      }
    }
  }
}

// stage 1: Pst = W1^T F (16 blk) | Q2 = W2 F1 (8 blk) | Q3 = W3 F2 (4 blk)
__global__ __launch_bounds__(256) void sgemm_stage1_k(
    const float* __restrict__ W1, const float* __restrict__ W2,
    const float* __restrict__ W3, const float* __restrict__ F,
    float* __restrict__ Pst, float* __restrict__ Q2, float* __restrict__ Q3) {
  __shared__ _Float16 As[128 * 40];
  __shared__ _Float16 Bs[128 * 40];
  int id = blockIdx.x;
  if (id < 16) {
    sgemm_dev(As, Bs, id & 3, id >> 2, W1, 512, 1, F, 512, Pst, nullptr, 512, 1.f);
  } else if (id < 24) {
    int j = id - 16;
    sgemm_dev(As, Bs, j & 3, j >> 2, W2, 256, 0, F, 512, Q2, nullptr, 256, 1.f);
  } else {
    int j = id - 24;
    sgemm_dev(As, Bs, j & 3, j >> 2, W3, 128, 0, F, 512, Q3, nullptr, 128, 1.f);
  }
}

// stage 2: M1T = Pst^T F | M2T = F^T Q2 | M3T = F^T Q3   (16 blocks each)
__global__ __launch_bounds__(256) void sgemm_stage2_k(
    const float* __restrict__ F, const float* __restrict__ Pst,
    const float* __restrict__ Q2, const float* __restrict__ Q3,
    _Float16* __restrict__ M1T, _Float16* __restrict__ M2T,
    _Float16* __restrict__ M3T) {
  __shared__ _Float16 As[128 * 40];
  __shared__ _Float16 Bs[128 * 40];
  int id = blockIdx.x;
  if (id < 16) {
    sgemm_dev(As, Bs, id & 3, id >> 2, Pst, 512, 1, F, 512, nullptr, M1T, 512, 1.f);
  } else if (id < 32) {
    int j = id - 16;
    sgemm_dev(As, Bs, j & 3, j >> 2, F, 512, 1, Q2, 512, nullptr, M2T, 256, 0.0078125f);
  } else {
    int j = id - 32;
    sgemm_dev(As, Bs, j & 3, j >> 2, F, 512, 1, Q3, 512, nullptr, M3T, 128, 0.0078125f);
  }
}

// ---------------- fp16 tiled transpose, two jobs per launch ----------------
// out[x*R + y(+off)] = in[y*C + x]; R is the OUT row stride.
__global__ __launch_bounds__(256) void transpose2_h_k(
    const _Float16* __restrict__ in0, _Float16* __restrict__ out0, int C0,
    const _Float16* __restrict__ in1, _Float16* __restrict__ out1, int C1,
    int xsplit, int R) {
  __shared__ _Float16 t[64][66];
  const _Float16* in;
  _Float16* out;
  int C, bx;
  if ((int)blockIdx.x < xsplit) { in = in0; out = out0; C = C0; bx = blockIdx.x; }
  else { in = in1; out = out1; C = C1; bx = blockIdx.x - xsplit; }
  int tid = threadIdx.x;
  int bxo = bx * 64;
  int by = blockIdx.y * 64;
  int cx = (tid & 15) * 4;
  int ry = tid >> 4;
#pragma unroll
  for (int p = 0; p < 4; p++) {
    int r = ry + p * 16;
    h4 v = *(const h4*)&in[(size_t)(by + r) * C + bxo + cx];
    t[r][cx + 0] = v[0]; t[r][cx + 1] = v[1]; t[r][cx + 2] = v[2]; t[r][cx + 3] = v[3];
  }
  __syncthreads();
#pragma unroll
  for (int p = 0; p < 4; p++) {
    int r2 = ry + p * 16;
    h4 v;
    v[0] = t[cx + 0][r2]; v[1] = t[cx + 1][r2]; v[2] = t[cx + 2][r2]; v[3] = t[cx + 3][r2];
    *(h4*)&out[(size_t)(bxo + r2) * R + by + cx] = v;
  }
}

// ---------------- main f16 MFMA GEMM (device fn, async16 staging) -----------
// MODE: 0 = fp16 out; 2 = dual-A dual-out fp16; 3 = fp32 out + rank-1;
//       4 = fp16 out + s_0^2 fixup (single stream).   KTOT = contraction len.
__device__ __forceinline__ void async16(const _Float16* g, _Float16* l) {
  __builtin_amdgcn_global_load_lds((const __attribute__((address_space(1))) void*)g,
                                   (__attribute__((address_space(3))) void*)l, 16, 0, 0);
}

template <int MODE, int KTOT>
__device__ void gemm_dev(_Float16* As, _Float16* Bs, int bx, int by,
                         const _Float16* __restrict__ A1, const _Float16* __restrict__ A2,
                         const _Float16* __restrict__ B1, const _Float16* __restrict__ B2,
                         void* __restrict__ C1, void* __restrict__ C2, int ldc, int coff,
                         const float* __restrict__ u, const float* __restrict__ wvec,
                         int sb, int tb) {
  constexpr bool DA = (MODE == 2);
  const int tid = threadIdx.x;
  const int lane = tid & 63;
  const int wm = (tid >> 6) & 1, wn = tid >> 7;
  const int m0 = by * 128, n0 = bx * 128;
  const int srow = tid >> 2, scol = (tid & 3) * 8;
  const int mask = (1 << sb) - 1;
  f4 acc[4][4] = {};
  f4 acc2[4][4] = {};
  const int fm = lane & 15, fko = (lane >> 4) * 8;
  for (int k0 = 0; k0 < KTOT; k0 += 32) {
#pragma unroll
    for (int i = 0; i < 2; i++) {
      int r = m0 + i * 64 + srow;
      int pr = ((r >> sb) << tb) | (r & mask);
      async16(A1 + (size_t)pr * KTOT + k0 + scol, &As[i * 2048 + tid * 8]);
      if constexpr (DA)
        async16(A2 + (size_t)pr * KTOT + k0 + scol, &As[4096 + i * 2048 + tid * 8]);
      int rb = n0 + i * 64 + srow;
      async16(B1 + (size_t)rb * KTOT + k0 + scol, &Bs[i * 2048 + tid * 8]);
    }
    __syncthreads();
    h8 af[4], bf[4], af2[4];
#pragma unroll
    for (int i = 0; i < 4; i++) {
      int ro = (wm * 64 + i * 16 + fm) * 32 + fko;
      af[i] = *(const h8*)&As[ro];
      if constexpr (DA) af2[i] = *(const h8*)&As[4096 + ro];
    }
#pragma unroll
    for (int j = 0; j < 4; j++) {
      int co = (wn * 64 + j * 16 + fm) * 32 + fko;
      bf[j] = *(const h8*)&Bs[co];
    }
#pragma unroll
    for (int i = 0; i < 4; i++)
#pragma unroll
      for (int j = 0; j < 4; j++) {
        acc[i][j] = MFMA16(af[i], bf[j], acc[i][j]);
        if constexpr (MODE == 2) acc2[i][j] = MFMA16(af2[i], bf[j], acc2[i][j]);
      }
    __syncthreads();
  }
  const int er = (lane >> 4) * 4, ec = lane & 15;
#pragma unroll
  for (int i = 0; i < 4; i++) {
    int gr0 = m0 + wm * 64 + i * 16 + er;
#pragma unroll
    for (int j = 0; j < 4; j++) {
      int gc = n0 + wn * 64 + j * 16 + ec;
#pragma unroll
      for (int r = 0; r < 4; r++) {
        size_t off = (size_t)(gr0 + r) * ldc + coff + gc;
        if constexpr (MODE == 3) {
          ((float*)C1)[off] = acc[i][j][r] + u[gr0 + r] * wvec[gc];
        } else if constexpr (MODE == 2) {
          ((_Float16*)C1)[off] = (_Float16)acc[i][j][r];
          ((_Float16*)C2)[off] = (_Float16)acc2[i][j][r];
        } else if constexpr (MODE == 4) {
          float v = acc[i][j][r];
          if ((gr0 + r) == 0 && gc < 512) v *= 0.5f;  // fused s_0^2 fixup (t=0,j=0)
          ((_Float16*)C1)[off] = (_Float16)v;
        } else {
          ((_Float16*)C1)[off] = (_Float16)acc[i][j][r];
        }
      }
    }
  }
}

// dispatch 5: G1 (blocks [0,512)) + independent branch-1 GEMM ([512,1536))
// G1: Zh = [Cm|Smn].[zcT;zsT] (K=1024, MODE 4). B1: out1 = Xh.M1T + v1 c1^T
// (K=512, MODE 3). B1 depends only on Xh/M1T — ready before this dispatch —
// and fills the CUs that G1's 512-block grid (2/CU) leaves underused.
__global__ __launch_bounds__(256) void gemm_g1b1_k(
    const _Float16* __restrict__ CSh, const _Float16* __restrict__ zT,
    _Float16* __restrict__ Zh, const _Float16* __restrict__ Xh,
    const _Float16* __restrict__ M1T, float* __restrict__ out,
    const float* __restrict__ v1, const float* __restrict__ c1) {
  __shared__ __align__(16) _Float16 As[4096];
  __shared__ __align__(16) _Float16 Bs[4096];
  int id = blockIdx.x;
  if (id < 512) {
    gemm_dev<4, 1024>(As, Bs, id & 127, id >> 7, CSh, nullptr, zT, nullptr, Zh,
                      nullptr, 16384, 0, nullptr, nullptr, 30, 30);
  } else {
    int j = id - 512;
    gemm_dev<3, 512>(As, Bs, j & 3, j >> 2, Xh, nullptr, M1T, nullptr, out,
                     nullptr, 1536, 0, v1, c1, 30, 30);
  }
}

// dispatch 6: Y2 = Zh M2T (by<128) | Y3 = Zh[j<16] M3T (by in [128,192))
__global__ __launch_bounds__(256) void gemm_duo_k(
    const _Float16* __restrict__ Zh, const _Float16* __restrict__ M2T,
    const _Float16* __restrict__ M3T, _Float16* __restrict__ Y2,
    _Float16* __restrict__ Y3) {
  __shared__ __align__(16) _Float16 As[4096];
  __shared__ __align__(16) _Float16 Bs[4096];
  int by = blockIdx.y;
  if (by < 128)
    gemm_dev<0, 512>(As, Bs, blockIdx.x, by, Zh, nullptr, M2T, nullptr, Y2, nullptr,
                     512, 0, nullptr, nullptr, 30, 30);
  else
    gemm_dev<0, 512>(As, Bs, blockIdx.x, by - 128, Zh, nullptr, M3T, nullptr, Y3,
                     nullptr, 512, 0, nullptr, nullptr, 4, 5);
}

// Pc2/Ps2 = CmT/SmT . Y2T (bx<128, ldc 16384) | Pc3/Ps3 = . Y3T (bx>=128, ldc 8192)
__global__ __launch_bounds__(256) void gemm2_pair_k(
    const _Float16* __restrict__ CmTh, const _Float16* __restrict__ SmTh,
    const _Float16* __restrict__ Y2T, const _Float16* __restrict__ Y3T,
    _Float16* __restrict__ Pc2, _Float16* __restrict__ Ps2,
    _Float16* __restrict__ Pc3, _Float16* __restrict__ Ps3) {
  __shared__ __align__(16) _Float16 As[2 * 4096];
  __shared__ __align__(16) _Float16 Bs[4096];
  if ((int)blockIdx.x < 128)
    gemm_dev<2, 512>(As, Bs, blockIdx.x, blockIdx.y, CmTh, SmTh, Y2T, nullptr, Pc2,
                     Ps2, 16384, 0, nullptr, nullptr, 30, 30);
  else
    gemm_dev<2, 512>(As, Bs, blockIdx.x - 128, blockIdx.y, CmTh, SmTh, Y3T, nullptr,
                     Pc3, Ps3, 8192, 0, nullptr, nullptr, 30, 30);
}

// ---------------- MFMA modulation (tables inline) ----------------
__global__ __launch_bounds__(256) void modmfma_k(
    const _Float16* __restrict__ Xh, _Float16* __restrict__ zc,
    _Float16* __restrict__ zs) {
  __shared__ _Float16 Bs[256 * 72];
  __shared__ _Float16 Ac[32 * 72];
  __shared__ _Float16 As[32 * 72];
  const int tid = threadIdx.x;
  const int lane = tid & 63;
  const int wid = tid >> 6;
  const int vp = blockIdx.y;
  const int l0 = blockIdx.x * 256;
  const float sc = 0.0078125f;
  {  // stage X transposed: lane -> k-row
    int r = lane;
    int u = r & 31;
    int n = (r < 32) ? ((u << 10) + vp) : ((u << 10) + 1023 - vp);
    const _Float16* src = Xh + (size_t)n * 512 + l0 + wid * 64;
#pragma unroll
    for (int i = 0; i < 8; i++) {
      h8 v = *(const h8*)(src + i * 8);
      int lb = wid * 64 + i * 8;
#pragma unroll
      for (int e = 0; e < 8; e++) Bs[(lb + e) * 72 + r] = v[e];
    }
  }
  for (int idx = tid; idx < 2048; idx += 256) {  // tables, trig inline
    int kk = idx & 63, j = idx >> 6;
    int u = kk & 31;
    int n = (kk < 32) ? ((u << 10) + vp) : ((u << 10) + 1023 - vp);
    int a = (j * (2 * n + 1)) & 131071;
    float sv, cv;
    __sincosf((float)(a * (PI_D / 65536.0)), &sv, &cv);
    Ac[j * 72 + kk] = (_Float16)(cv * sc);
    As[j * 72 + kk] = (_Float16)(((kk < 32) ? sv : -sv) * sc);
  }
  __syncthreads();
  const int fm = lane & 15, fko = (lane >> 4) * 8;
  f4 accc[2][4] = {};
  f4 accs[2][4] = {};
#pragma unroll
  for (int ks = 0; ks < 2; ks++) {
    int ko = ks * 32 + fko;
    h8 afc[2], afs[2], bf[4];
#pragma unroll
    for (int i = 0; i < 2; i++) {
      afc[i] = *(const h8*)&Ac[(i * 16 + fm) * 72 + ko];
      afs[i] = *(const h8*)&As[(i * 16 + fm) * 72 + ko];
    }
#pragma unroll
    for (int j = 0; j < 4; j++)
      bf[j] = *(const h8*)&Bs[(wid * 64 + j * 16 + fm) * 72 + ko];
#pragma unroll
    for (int i = 0; i < 2; i++)
#pragma unroll
      for (int j = 0; j < 4; j++) {
        accc[i][j] = MFMA16(afc[i], bf[j], accc[i][j]);
        accs[i][j] = MFMA16(afs[i], bf[j], accs[i][j]);
      }
  }
  const int er = (lane >> 4) * 4, ec = lane & 15;
#pragma unroll
  for (int i = 0; i < 2; i++)
#pragma unroll
    for (int j = 0; j < 4; j++)
#pragma unroll
      for (int r = 0; r < 4; r++) {
        int row = i * 16 + er + r;
        int col = l0 + wid * 64 + j * 16 + ec;
        size_t off = (size_t)vp * 16384 + row * 512 + col;
        zc[off] = (_Float16)accc[i][j][r];
        zs[off] = (_Float16)accs[i][j][r];
      }
}

// ---------------- MFMA demodulation (tables inline, both branches fused) ----
template <int JC>
__device__ void demod_dev(char* smemraw, const _Float16* __restrict__ Pc,
                          const _Float16* __restrict__ Ps,
                          const float* __restrict__ wv, const float* __restrict__ cw,
                          float* __restrict__ out, int coff) {
  constexpr int K2 = 2 * JC;
  constexpr int ST = K2 + 8;
  _Float16* Bs = (_Float16*)smemraw;                          // 256*ST
  _Float16* At = (_Float16*)(smemraw + (size_t)256 * ST * 2); // 64*ST
  const int tid = threadIdx.x;
  const int lane = tid & 63;
  const int wid = tid >> 6;
  const int vp = blockIdx.y;
  const int l0 = blockIdx.x * 256;
  {  // stage P transposed
    constexpr int CPL = 64 / K2;
    int r = lane & (K2 - 1);
    int chunk = wid * CPL + (CPL == 1 ? 0 : (lane >> 5));
    int lb = chunk * K2;
    const _Float16* src = (r < JC ? Pc + (size_t)vp * (JC * 512) + r * 512
                                  : Ps + (size_t)vp * (JC * 512) + (r - JC) * 512) +
                          l0 + lb;
#pragma unroll
    for (int i = 0; i < K2 / 8; i++) {
      h8 v = *(const h8*)(src + i * 8);
#pragma unroll
      for (int e = 0; e < 8; e++) Bs[(lb + i * 8 + e) * ST + r] = v[e];
    }
  }
  for (int idx = tid; idx < 64 * K2; idx += 256) {  // tables, trig inline
    int kk = idx & (K2 - 1), m = idx / K2;
    int ab = m >> 5, u = m & 31;
    int n = ab ? ((u << 10) + 1023 - vp) : ((u << 10) + vp);
    int twon = 2 * n + 1;
    float val;
    if (kk < JC) {
      int a = (kk * twon) & 131071;
      val = cosf((float)(a * (PI_D / 65536.0)));
    } else {
      int a = ((kk - JC) * twon) & 131071;
      float sv = sinf((float)(a * (PI_D / 65536.0)));
      val = ab ? sv : -sv;
    }
    At[m * ST + kk] = (_Float16)val;
  }
  __syncthreads();
  const int fm = lane & 15, fko = (lane >> 4) * 8;
  f4 acc[4][4] = {};
#pragma unroll
  for (int ks = 0; ks < K2 / 32; ks++) {
    int ko = ks * 32 + fko;
    h8 af[4], bf[4];
#pragma unroll
    for (int i = 0; i < 4; i++) af[i] = *(const h8*)&At[(i * 16 + fm) * ST + ko];
#pragma unroll
    for (int j = 0; j < 4; j++) bf[j] = *(const h8*)&Bs[(wid * 64 + j * 16 + fm) * ST + ko];
#pragma unroll
    for (int i = 0; i < 4; i++)
#pragma unroll
      for (int j = 0; j < 4; j++) acc[i][j] = MFMA16(af[i], bf[j], acc[i][j]);
  }
  const int er = (lane >> 4) * 4, ec = lane & 15;
#pragma unroll
  for (int i = 0; i < 4; i++)
#pragma unroll
    for (int j = 0; j < 4; j++) {
      int col = l0 + wid * 64 + j * 16 + ec;
      float cl = cw[col];
#pragma unroll
      for (int r = 0; r < 4; r++) {
        int m = i * 16 + er + r;
        int ab = m >> 5, u = m & 31;
        int n = ab ? ((u << 10) + 1023 - vp) : ((u << 10) + vp);
        out[(size_t)n * 1536 + coff + col] = acc[i][j][r] + wv[n] * cl;
      }
    }
}

__global__ __launch_bounds__(256) void demod_pair_k(
    const _Float16* __restrict__ Pc2, const _Float16* __restrict__ Ps2,
    const float* __restrict__ w2v, const float* __restrict__ c2,
    const _Float16* __restrict__ Pc3, const _Float16* __restrict__ Ps3,
    const float* __restrict__ w3v, const float* __restrict__ c3,
    float* __restrict__ out) {
  __shared__ __align__(16) char smem[256 * 72 * 2 + 64 * 72 * 2];  // 46080 B
  if (blockIdx.z == 0)
    demod_dev<32>(smem, Pc2, Ps2, w2v, c2, out, 512);
  else
    demod_dev<16>(smem, Pc3, Ps3, w3v, c3, out, 1024);
}

// ---------------- launch ----------------
extern "C" void kernel_launch(void* const* d_in, const int* in_sizes, int n_in,
                              void* d_out, int out_size, void* d_ws, size_t ws_size,
                              hipStream_t stream) {
  const float* X  = (const float*)d_in[0];
  const float* W1 = (const float*)d_in[1];
  const float* b1 = (const float*)d_in[2];
  const float* W2 = (const float*)d_in[3];
  const float* b2 = (const float*)d_in[4];
  const float* W3 = (const float*)d_in[5];
  const float* b3 = (const float*)d_in[6];
  float* out = (float*)d_out;
  char* w = (char*)d_ws;
  const size_t MB = 1024 * 1024;

  float* F    = (float*)(w);
  float* v1   = (float*)(w + 9 * MB);
  float* w2v  = (float*)(w + 9 * MB + 131072);
  float* w3v  = (float*)(w + 9 * MB + 262144);
  float* c1   = (float*)(w + 9 * MB + 393216);
  float* c2   = (float*)(w + 9 * MB + 395264);
  float* c3   = (float*)(w + 9 * MB + 397312);
  float* Pst  = (float*)(w + 10 * MB);             // 1 MB fp32
  _Float16* CmTh = (_Float16*)(w + 11 * MB);
  _Float16* SmTh = (_Float16*)(w + 11 * MB + 524288);
  _Float16* CSh  = (_Float16*)(w + 12 * MB);       // [512][1024] cos|-sin, 1 MB
  _Float16* M1T  = (_Float16*)(w + 13 * MB);
  _Float16* M2T  = (_Float16*)(w + 13 * MB + 524288);
  _Float16* M3T  = (_Float16*)(w + 14 * MB);
  float* Q2      = (float*)(w + 14 * MB + 524288); // 512 KB fp32
  float* Q3      = (float*)(w + 15 * MB);          // 256 KB fp32
  _Float16* Xh   = (_Float16*)(w + 16 * MB);       // 32 MB
  _Float16* zc   = (_Float16*)(w + 48 * MB);       // 16 MB
  _Float16* zs   = (_Float16*)(w + 64 * MB);       // 16 MB
  _Float16* Pc2h = (_Float16*)(w + 48 * MB);       // over zc (dead)
  _Float16* Ps2h = (_Float16*)(w + 64 * MB);       // over zs (dead)
  _Float16* Pc3h = (_Float16*)(w + 104 * MB);      // 8 MB
  _Float16* Ps3h = (_Float16*)(w + 112 * MB);      // 8 MB, over Zh (dead)
  _Float16* zT   = (_Float16*)(w + 80 * MB);       // [16384][1024], 32 MB (80-112)
  _Float16* Y2T  = (_Float16*)(w + 80 * MB);       // over zT (dead)
  _Float16* Y3T  = (_Float16*)(w + 96 * MB);       // 8 MB over zT (dead)
  _Float16* Zh   = (_Float16*)(w + 112 * MB);      // 16 MB
  _Float16* Y2   = (_Float16*)(w + 128 * MB);      // 16 MB
  _Float16* Y3   = (_Float16*)(w + 144 * MB);      // 8 MB

  // 1. F + tables (CS packed) + rank-1 vectors + c-vectors
  megafill_k<<<2560, 256, 0, stream>>>(F, CSh, CmTh, SmTh, v1, w2v, w3v,
                                       b1, b2, b3, c1, c2, c3);
  // 2-3. M-matrix sandwich GEMMs
  sgemm_stage1_k<<<28, 256, 0, stream>>>(W1, W2, W3, F, Pst, Q2, Q3);
  sgemm_stage2_k<<<48, 256, 0, stream>>>(F, Pst, Q2, Q3, M1T, M2T, M3T);
  // 4. X -> fp16
  conv_xh_k<<<16384, 256, 0, stream>>>(X, Xh);
  // 5. modulation (tables inline)
  modmfma_k<<<dim3(2, 512), 256, 0, stream>>>(Xh, zc, zs);
  // 6. zc/zs transpose into stacked zT[16384][1024]
  transpose2_h_k<<<dim3(512, 8), 256, 0, stream>>>(zc, zT, 16384, zs, zT + 512,
                                                   16384, 256, 1024);
  // 7. forward GEMM (K=1024) + independent branch-1 GEMM (CU-fill packing)
  gemm_g1b1_k<<<1536, 256, 0, stream>>>(CSh, zT, Zh, Xh, M1T, out, v1, c1);
  // 8. coefficient GEMMs Y2+Y3
  gemm_duo_k<<<dim3(4, 192), 256, 0, stream>>>(Zh, M2T, M3T, Y2, Y3);
  // 9. Y2/Y3 transpose (fused pair)
  transpose2_h_k<<<dim3(384, 8), 256, 0, stream>>>(Y2, Y2T, 16384, Y3, Y3T, 8192,
                                                   256, 512);
  // 10. inverse shared GEMMs (fused branch2+branch3)
  gemm2_pair_k<<<dim3(192, 4), 256, 0, stream>>>(CmTh, SmTh, Y2T, Y3T, Pc2h, Ps2h,
                                                 Pc3h, Ps3h);
  // 11. demodulation, both branches (tables inline)
  demod_pair_k<<<dim3(2, 512, 2), 256, 0, stream>>>(Pc2h, Ps2h, w2v, c2, Pc3h, Ps3h,
                                                    w3v, c3, out);
}

// Round 12
// 576.750 us; speedup vs baseline: 1.0350x; 1.0013x over previous
//
#include <hip/hip_runtime.h>
#include <cstddef>

// ============================================================================
// MultiWaveletTransform — algebraic refactor, all heavy math on MFMA.
// Round 12: R11 base (577.5us verified) + the same CU-fill packing lever
// applied to the two underfilled precompute GEMMs:
//  (a) conv_xh (16384 blk, independent) + sgemm_stage1 (28 blk) -> 1 dispatch
//  (b) modmfma (1024 blk, reads Xh fp16 — the PROVEN path, not R8's X-direct)
//      + sgemm_stage2 (48 blk) -> 1 dispatch.
// 11 -> 9 dispatches.
// ============================================================================

#define PI_D 3.14159265358979323846

typedef _Float16 h8 __attribute__((ext_vector_type(8)));
typedef _Float16 h4 __attribute__((ext_vector_type(4)));
typedef float f4 __attribute__((ext_vector_type(4)));

#define MFMA16(a, b, c) __builtin_amdgcn_mfma_f32_16x16x32_f16(a, b, c, 0, 0, 0)

// ---------------- dispatch 1: F + tables + vectors + c-vecs ----------------
// blocks [0,1024): F        [1024,2048): CS (cos|-sin packed) + CmT/SmT
// [2048,2176): v1/w2/w3     [2176,2560): c1/c2/c3 = F^T b
__global__ __launch_bounds__(256) void megafill_k(
    float* __restrict__ F, _Float16* __restrict__ CSh,
    _Float16* __restrict__ CmTh, _Float16* __restrict__ SmTh,
    float* __restrict__ v1, float* __restrict__ w2, float* __restrict__ w3,
    const float* __restrict__ b1, const float* __restrict__ b2,
    const float* __restrict__ b3, float* __restrict__ c1, float* __restrict__ c2,
    float* __restrict__ c3) {
  const int blk = blockIdx.x;
  const int tid = threadIdx.x;
  if (blk < 1024) {
    int idx = blk * 256 + tid;
    int k = idx >> 9, m = idx & 511;
    int a = (k * (2 * m + 1)) & 2047;
    float ang = (float)(a * (PI_D / 1024.0));
    float s = (k == 0) ? 0.04419417382415922f : 0.0625f;
    F[idx] = s * cosf(ang);
  } else if (blk < 2048) {
    int idx = (blk - 1024) * 256 + tid;
    int t = idx >> 9, v = idx & 511;
    int a = (t * (2 * v + 1)) & 2047;
    float ang = (float)(a * (PI_D / 1024.0));
    float c = cosf(ang), s = sinf(ang);
    CSh[t * 1024 + v] = (_Float16)c;          // cos half (k = 0..511)
    CSh[t * 1024 + 512 + v] = (_Float16)(-s); // -sin half (k = 512..1023)
    CmTh[v * 512 + t] = (_Float16)c;
    SmTh[v * 512 + t] = (_Float16)s;
  } else if (blk < 2176) {
    int n = (blk - 2048) * 256 + tid;
    const double s1 = 0.005524271728019903;
    const double s2 = 0.0078125;
    double th = (2 * n + 1) * (PI_D / 65536.0);
    double c = cos(th), s = sin(th);
    double Dr = 1.0 - c, Di = -s;
    double dd = Dr * Dr + Di * Di;
    double Nr = 1.0, Ni = (n & 1) ? 1.0 : -1.0;
    double vre = (Nr * Dr + Ni * Di) / dd;
    v1[n] = (float)(s2 * vre + (s1 - s2));
    int m64 = (2 * n + 1) & 2047;
    double a64 = m64 * (PI_D / 1024.0);
    double D64r = 1.0 - cos(a64), D64i = -sin(a64);
    double d64 = D64r * D64r + D64i * D64i;
    double Gr = (Nr * D64r + Ni * D64i) / d64;
    double Gi = (Ni * D64r - Nr * D64i) / d64;
    int m32 = (2 * n + 1) & 4095;
    double a32 = m32 * (PI_D / 2048.0);
    double S32nr = 1.0 - cos(a32), S32ni = -sin(a32);
    double S32r = (S32nr * Dr + S32ni * Di) / dd;
    double S32i = (S32ni * Dr - S32nr * Di) / dd;
    w2[n] = (float)(s2 * (S32r * Gr - S32i * Gi) + (s1 - s2));
    int m16 = (2 * n + 1) & 8191;
    double a16 = m16 * (PI_D / 4096.0);
    double S16nr = 1.0 - cos(a16), S16ni = -sin(a16);
    double S16r = (S16nr * Dr + S16ni * Di) / dd;
    double S16i = (S16ni * Dr - S16nr * Di) / dd;
    w3[n] = (float)(s2 * (S16r * Gr - S16i * Gi) + (s1 - s2));
  } else {
    // c_i[l] = sum_m F[m][l] * b_i[m], one wave per (branch,l)
    int gid = (blk - 2176) * 4 + (tid >> 6);
    int lane = tid & 63;
    int branch = gid >> 9;
    int l = gid & 511;
    int K = 512 >> branch;
    const float* b = (branch == 0) ? b1 : (branch == 1) ? b2 : b3;
    float acc = 0.f;
    for (int m = lane; m < K; m += 64) {
      int a = (m * (2 * l + 1)) & 2047;
      float s = (m == 0) ? 0.04419417382415922f : 0.0625f;
      acc += s * cosf((float)(a * (PI_D / 1024.0))) * b[m];
    }
#pragma unroll
    for (int o = 32; o > 0; o >>= 1) acc += __shfl_down(acc, o, 64);
    if (lane == 0) {
      float* c = (branch == 0) ? c1 : (branch == 1) ? c2 : c3;
      c[l] = acc;
    }
  }
}

// ---------------- small MFMA GEMM for precompute (device fn) ----------------
// C[m][n] = sum_k A'[k][m] * B[k][n]  (B always [K][N] fp32, transpose-staged;
// A: transA=1 -> A[k][m], transA=0 -> A[m][k]).  Out fp32 or f16*scale, ldc=512.
__device__ void sgemm_dev(_Float16* As, _Float16* Bs, int bx, int by,
                          const float* __restrict__ A, int lda, int transA,
                          const float* __restrict__ B, int ldb,
                          float* __restrict__ Cf, _Float16* __restrict__ C16,
                          int K, float scale) {
  const int tid = threadIdx.x;
  const int lane = tid & 63;
  const int wm = (tid >> 6) & 1, wn = tid >> 7;
  const int m0 = by * 128, n0 = bx * 128;
  const int fm = lane & 15, fko = (lane >> 4) * 8;
  f4 acc[4][4] = {};
  for (int k0 = 0; k0 < K; k0 += 32) {
    if (transA) {
#pragma unroll
      for (int i = 0; i < 4; i++) {
        int idx4 = tid + i * 256;
        int kk = idx4 & 31, mc = (idx4 >> 5) * 4;
        float4 v = *(const float4*)&A[(size_t)(k0 + kk) * lda + m0 + mc];
        As[(mc + 0) * 40 + kk] = (_Float16)v.x;
        As[(mc + 1) * 40 + kk] = (_Float16)v.y;
        As[(mc + 2) * 40 + kk] = (_Float16)v.z;
        As[(mc + 3) * 40 + kk] = (_Float16)v.w;
      }
    } else {
#pragma unroll
      for (int i = 0; i < 4; i++) {
        int idx4 = tid + i * 256;
        int mm = idx4 >> 3, kc = (idx4 & 7) * 4;
        float4 v = *(const float4*)&A[(size_t)(m0 + mm) * lda + k0 + kc];
        h4 o;
        o[0] = (_Float16)v.x; o[1] = (_Float16)v.y; o[2] = (_Float16)v.z; o[3] = (_Float16)v.w;
        *(h4*)&As[mm * 40 + kc] = o;
      }
    }
#pragma unroll
    for (int i = 0; i < 4; i++) {
      int idx4 = tid + i * 256;
      int kk = idx4 & 31, nc = (idx4 >> 5) * 4;
      float4 v = *(const float4*)&B[(size_t)(k0 + kk) * ldb + n0 + nc];
      Bs[(nc + 0) * 40 + kk] = (_Float16)v.x;
      Bs[(nc + 1) * 40 + kk] = (_Float16)v.y;
      Bs[(nc + 2) * 40 + kk] = (_Float16)v.z;
      Bs[(nc + 3) * 40 + kk] = (_Float16)v.w;
    }
    __syncthreads();
    h8 af[4], bf[4];
#pragma unroll
    for (int i = 0; i < 4; i++) af[i] = *(const h8*)&As[(wm * 64 + i * 16 + fm) * 40 + fko];
#pragma unroll
    for (int j = 0; j < 4; j++) bf[j] = *(const h8*)&Bs[(wn * 64 + j * 16 + fm) * 40 + fko];
#pragma unroll
    for (int i = 0; i < 4; i++)
#pragma unroll
      for (int j = 0; j < 4; j++) acc[i][j] = MFMA16(af[i], bf[j], acc[i][j]);
    __syncthreads();
  }
  const int er = (lane >> 4) * 4, ec = lane & 15;
#pragma unroll
  for (int i = 0; i < 4; i++) {
    int gr0 = m0 + wm * 64 + i * 16 + er;
#pragma unroll
    for (int j = 0; j < 4; j++) {
      int gc = n0 + wn * 64 + j * 16 + ec;
#pragma unroll
      for (int r = 0; r < 4; r++) {
        size_t off = (size_t)(gr0 + r) * 512 + gc;
        if (C16) C16[off] = (_Float16)(acc[i][j][r] * scale);
        else Cf[off] = acc[i][j][r];
      }
    }
  }
}

// ---------------- dispatch 2: conv X->fp16 + sgemm stage 1 ------------------
// blocks [0,16384): conv   [16384,16412): Pst/Q2/Q3 (F from memory)
__global__ __launch_bounds__(256) void conv_s1_k(
    const float* __restrict__ X, _Float16* __restrict__ Xh,
    const float* __restrict__ W1, const float* __restrict__ W2,
    const float* __restrict__ W3, const float* __restrict__ F,
    float* __restrict__ Pst, float* __restrict__ Q2, float* __restrict__ Q3) {
  __shared__ _Float16 As[128 * 40];
  __shared__ _Float16 Bs[128 * 40];
  const int blk = blockIdx.x;
  if (blk < 16384) {
    int i = blk * 256 + threadIdx.x;
    float4 v = ((const float4*)X)[i];
    h4 o;
    o[0] = (_Float16)v.x; o[1] = (_Float16)v.y; o[2] = (_Float16)v.z; o[3] = (_Float16)v.w;
    ((h4*)Xh)[i] = o;
  } else {
    int id = blk - 16384;
    if (id < 16) {         // Pst = W1^T F
      sgemm_dev(As, Bs, id & 3, id >> 2, W1, 512, 1, F, 512, Pst, nullptr, 512, 1.f);
    } else if (id < 24) {  // Q2 = W2 F1
      int j = id - 16;
      sgemm_dev(As, Bs, j & 3, j >> 2, W2, 256, 0, F, 512, Q2, nullptr, 256, 1.f);
    } else {               // Q3 = W3 F2
      int j = id - 24;
      sgemm_dev(As, Bs, j & 3, j >> 2, W3, 128, 0, F, 512, Q3, nullptr, 128, 1.f);
    }
  }
}

// ---------------- modulation device fn (reads Xh fp16 — proven path) --------
__device__ void modmfma_dev(char* smemraw, const _Float16* __restrict__ Xh,
                            _Float16* __restrict__ zc, _Float16* __restrict__ zs,
                            int vp, int l0) {
  _Float16* Bs = (_Float16*)smemraw;                 // 256*72 h = 36864 B
  _Float16* Ac = (_Float16*)(smemraw + 36864);       // 32*72 h = 4608 B
  _Float16* As = (_Float16*)(smemraw + 41472);       // 32*72 h = 4608 B
  const int tid = threadIdx.x;
  const int lane = tid & 63;
  const int wid = tid >> 6;
  const float sc = 0.0078125f;
  {  // stage X transposed: lane -> k-row
    int r = lane;
    int u = r & 31;
    int n = (r < 32) ? ((u << 10) + vp) : ((u << 10) + 1023 - vp);
    const _Float16* src = Xh + (size_t)n * 512 + l0 + wid * 64;
#pragma unroll
    for (int i = 0; i < 8; i++) {
      h8 v = *(const h8*)(src + i * 8);
      int lb = wid * 64 + i * 8;
#pragma unroll
      for (int e = 0; e < 8; e++) Bs[(lb + e) * 72 + r] = v[e];
    }
  }
  for (int idx = tid; idx < 2048; idx += 256) {  // tables, trig inline
    int kk = idx & 63, j = idx >> 6;
    int u = kk & 31;
    int n = (kk < 32) ? ((u << 10) + vp) : ((u << 10) + 1023 - vp);
    int a = (j * (2 * n + 1)) & 131071;
    float sv, cv;
    __sincosf((float)(a * (PI_D / 65536.0)), &sv, &cv);
    Ac[j * 72 + kk] = (_Float16)(cv * sc);
    As[j * 72 + kk] = (_Float16)(((kk < 32) ? sv : -sv) * sc);
  }
  __syncthreads();
  const int fm = lane & 15, fko = (lane >> 4) * 8;
  f4 accc[2][4] = {};
  f4 accs[2][4] = {};
#pragma unroll
  for (int ks = 0; ks < 2; ks++) {
    int ko = ks * 32 + fko;
    h8 afc[2], afs[2], bf[4];
#pragma unroll
    for (int i = 0; i < 2; i++) {
      afc[i] = *(const h8*)&Ac[(i * 16 + fm) * 72 + ko];
      afs[i] = *(const h8*)&As[(i * 16 + fm) * 72 + ko];
    }
#pragma unroll
    for (int j = 0; j < 4; j++)
      bf[j] = *(const h8*)&Bs[(wid * 64 + j * 16 + fm) * 72 + ko];
#pragma unroll
    for (int i = 0; i < 2; i++)
#pragma unroll
      for (int j = 0; j < 4; j++) {
        accc[i][j] = MFMA16(afc[i], bf[j], accc[i][j]);
        accs[i][j] = MFMA16(afs[i], bf[j], accs[i][j]);
      }
  }
  const int er = (lane >> 4) * 4, ec = lane & 15;
#pragma unroll
  for (int i = 0; i < 2; i++)
#pragma unroll
    for (int j = 0; j < 4; j++)
#pragma unroll
      for (int r = 0; r < 4; r++) {
        int row = i * 16 + er + r;
        int col = l0 + wid * 64 + j * 16 + ec;
        size_t off = (size_t)vp * 16384 + row * 512 + col;
        zc[off] = (_Float16)accc[i][j][r];
        zs[off] = (_Float16)accs[i][j][r];
      }
}

// ---------------- dispatch 3: modulation + sgemm stage 2 --------------------
// blocks [0,1024): modmfma (vp = blk>>1, l0 = (blk&1)*256)
// [1024,1072): M1T/M2T/M3T (F from memory)
__global__ __launch_bounds__(256) void mod_s2_k(
    const _Float16* __restrict__ Xh, _Float16* __restrict__ zc,
    _Float16* __restrict__ zs, const float* __restrict__ F,
    const float* __restrict__ Pst, const float* __restrict__ Q2,
    const float* __restrict__ Q3, _Float16* __restrict__ M1T,
    _Float16* __restrict__ M2T, _Float16* __restrict__ M3T) {
  __shared__ __align__(16) char smem[46080];
  const int blk = blockIdx.x;
  if (blk < 1024) {
    modmfma_dev(smem, Xh, zc, zs, blk >> 1, (blk & 1) * 256);
  } else {
    _Float16* As = (_Float16*)smem;
    _Float16* Bs = (_Float16*)(smem + 128 * 40 * 2);
    int id = blk - 1024;
    if (id < 16) {         // M1T = Pst^T F
      sgemm_dev(As, Bs, id & 3, id >> 2, Pst, 512, 1, F, 512, nullptr, M1T, 512, 1.f);
    } else if (id < 32) {  // M2T = F^T Q2
      int j = id - 16;
      sgemm_dev(As, Bs, j & 3, j >> 2, F, 512, 1, Q2, 512, nullptr, M2T, 256, 0.0078125f);
    } else {               // M3T = F^T Q3
      int j = id - 32;
      sgemm_dev(As, Bs, j & 3, j >> 2, F, 512, 1, Q3, 512, nullptr, M3T, 128, 0.0078125f);
    }
  }
}

// ---------------- fp16 tiled transpose, two jobs per launch ----------------
// out[x*R + y(+off)] = in[y*C + x]; R is the OUT row stride.
__global__ __launch_bounds__(256) void transpose2_h_k(
    const _Float16* __restrict__ in0, _Float16* __restrict__ out0, int C0,
    const _Float16* __restrict__ in1, _Float16* __restrict__ out1, int C1,
    int xsplit, int R) {
  __shared__ _Float16 t[64][66];
  const _Float16* in;
  _Float16* out;
  int C, bx;
  if ((int)blockIdx.x < xsplit) { in = in0; out = out0; C = C0; bx = blockIdx.x; }
  else { in = in1; out = out1; C = C1; bx = blockIdx.x - xsplit; }
  int tid = threadIdx.x;
  int bxo = bx * 64;
  int by = blockIdx.y * 64;
  int cx = (tid & 15) * 4;
  int ry = tid >> 4;
#pragma unroll
  for (int p = 0; p < 4; p++) {
    int r = ry + p * 16;
    h4 v = *(const h4*)&in[(size_t)(by + r) * C + bxo + cx];
    t[r][cx + 0] = v[0]; t[r][cx + 1] = v[1]; t[r][cx + 2] = v[2]; t[r][cx + 3] = v[3];
  }
  __syncthreads();
#pragma unroll
  for (int p = 0; p < 4; p++) {
    int r2 = ry + p * 16;
    h4 v;
    v[0] = t[cx + 0][r2]; v[1] = t[cx + 1][r2]; v[2] = t[cx + 2][r2]; v[3] = t[cx + 3][r2];
    *(h4*)&out[(size_t)(bxo + r2) * R + by + cx] = v;
  }
}

// ---------------- main f16 MFMA GEMM (device fn, async16 staging) -----------
// MODE: 0 = fp16 out; 2 = dual-A dual-out fp16; 3 = fp32 out + rank-1;
//       4 = fp16 out + s_0^2 fixup (single stream).   KTOT = contraction len.
__device__ __forceinline__ void async16(const _Float16* g, _Float16* l) {
  __builtin_amdgcn_global_load_lds((const __attribute__((address_space(1))) void*)g,
                                   (__attribute__((address_space(3))) void*)l, 16, 0, 0);
}

template <int MODE, int KTOT>
__device__ void gemm_dev(_Float16* As, _Float16* Bs, int bx, int by,
                         const _Float16* __restrict__ A1, const _Float16* __restrict__ A2,
                         const _Float16* __restrict__ B1, const _Float16* __restrict__ B2,
                         void* __restrict__ C1, void* __restrict__ C2, int ldc, int coff,
                         const float* __restrict__ u, const float* __restrict__ wvec,
                         int sb, int tb) {
  constexpr bool DA = (MODE == 2);
  const int tid = threadIdx.x;
  const int lane = tid & 63;
  const int wm = (tid >> 6) & 1, wn = tid >> 7;
  const int m0 = by * 128, n0 = bx * 128;
  const int srow = tid >> 2, scol = (tid & 3) * 8;
  const int mask = (1 << sb) - 1;
  f4 acc[4][4] = {};
  f4 acc2[4][4] = {};
  const int fm = lane & 15, fko = (lane >> 4) * 8;
  for (int k0 = 0; k0 < KTOT; k0 += 32) {
#pragma unroll
    for (int i = 0; i < 2; i++) {
      int r = m0 + i * 64 + srow;
      int pr = ((r >> sb) << tb) | (r & mask);
      async16(A1 + (size_t)pr * KTOT + k0 + scol, &As[i * 2048 + tid * 8]);
      if constexpr (DA)
        async16(A2 + (size_t)pr * KTOT + k0 + scol, &As[4096 + i * 2048 + tid * 8]);
      int rb = n0 + i * 64 + srow;
      async16(B1 + (size_t)rb * KTOT + k0 + scol, &Bs[i * 2048 + tid * 8]);
    }
    __syncthreads();
    h8 af[4], bf[4], af2[4];
#pragma unroll
    for (int i = 0; i < 4; i++) {
      int ro = (wm * 64 + i * 16 + fm) * 32 + fko;
      af[i] = *(const h8*)&As[ro];
      if constexpr (DA) af2[i] = *(const h8*)&As[4096 + ro];
    }
#pragma unroll
    for (int j = 0; j < 4; j++) {
      int co = (wn * 64 + j * 16 + fm) * 32 + fko;
      bf[j] = *(const h8*)&Bs[co];
    }
#pragma unroll
    for (int i = 0; i < 4; i++)
#pragma unroll
      for (int j = 0; j < 4; j++) {
        acc[i][j] = MFMA16(af[i], bf[j], acc[i][j]);
        if constexpr (MODE == 2) acc2[i][j] = MFMA16(af2[i], bf[j], acc2[i][j]);
      }
    __syncthreads();
  }
  const int er = (lane >> 4) * 4, ec = lane & 15;
#pragma unroll
  for (int i = 0; i < 4; i++) {
    int gr0 = m0 + wm * 64 + i * 16 + er;
#pragma unroll
    for (int j = 0; j < 4; j++) {
      int gc = n0 + wn * 64 + j * 16 + ec;
#pragma unroll
      for (int r = 0; r < 4; r++) {
        size_t off = (size_t)(gr0 + r) * ldc + coff + gc;
        if constexpr (MODE == 3) {
          ((float*)C1)[off] = acc[i][j][r] + u[gr0 + r] * wvec[gc];
        } else if constexpr (MODE == 2) {
          ((_Float16*)C1)[off] = (_Float16)acc[i][j][r];
          ((_Float16*)C2)[off] = (_Float16)acc2[i][j][r];
        } else if constexpr (MODE == 4) {
          float v = acc[i][j][r];
          if ((gr0 + r) == 0 && gc < 512) v *= 0.5f;  // fused s_0^2 fixup (t=0,j=0)
          ((_Float16*)C1)[off] = (_Float16)v;
        } else {
          ((_Float16*)C1)[off] = (_Float16)acc[i][j][r];
        }
      }
    }
  }
}

// dispatch 5: G1 (blocks [0,512)) + independent branch-1 GEMM ([512,1536))
// G1: Zh = [Cm|Smn].[zcT;zsT] (K=1024, MODE 4). B1: out1 = Xh.M1T + v1 c1^T
// (K=512, MODE 3).
__global__ __launch_bounds__(256) void gemm_g1b1_k(
    const _Float16* __restrict__ CSh, const _Float16* __restrict__ zT,
    _Float16* __restrict__ Zh, const _Float16* __restrict__ Xh,
    const _Float16* __restrict__ M1T, float* __restrict__ out,
    const float* __restrict__ v1, const float* __restrict__ c1) {
  __shared__ __align__(16) _Float16 As[4096];
  __shared__ __align__(16) _Float16 Bs[4096];
  int id = blockIdx.x;
  if (id < 512) {
    gemm_dev<4, 1024>(As, Bs, id & 127, id >> 7, CSh, nullptr, zT, nullptr, Zh,
                      nullptr, 16384, 0, nullptr, nullptr, 30, 30);
  } else {
    int j = id - 512;
    gemm_dev<3, 512>(As, Bs, j & 3, j >> 2, Xh, nullptr, M1T, nullptr, out,
                     nullptr, 1536, 0, v1, c1, 30, 30);
  }
}

// dispatch 6: Y2 = Zh M2T (by<128) | Y3 = Zh[j<16] M3T (by in [128,192))
__global__ __launch_bounds__(256) void gemm_duo_k(
    const _Float16* __restrict__ Zh, const _Float16* __restrict__ M2T,
    const _Float16* __restrict__ M3T, _Float16* __restrict__ Y2,
    _Float16* __restrict__ Y3) {
  __shared__ __align__(16) _Float16 As[4096];
  __shared__ __align__(16) _Float16 Bs[4096];
  int by = blockIdx.y;
  if (by < 128)
    gemm_dev<0, 512>(As, Bs, blockIdx.x, by, Zh, nullptr, M2T, nullptr, Y2, nullptr,
                     512, 0, nullptr, nullptr, 30, 30);
  else
    gemm_dev<0, 512>(As, Bs, blockIdx.x, by - 128, Zh, nullptr, M3T, nullptr, Y3,
                     nullptr, 512, 0, nullptr, nullptr, 4, 5);
}

// Pc2/Ps2 = CmT/SmT . Y2T (bx<128, ldc 16384) | Pc3/Ps3 = . Y3T (bx>=128, ldc 8192)
__global__ __launch_bounds__(256) void gemm2_pair_k(
    const _Float16* __restrict__ CmTh, const _Float16* __restrict__ SmTh,
    const _Float16* __restrict__ Y2T, const _Float16* __restrict__ Y3T,
    _Float16* __restrict__ Pc2, _Float16* __restrict__ Ps2,
    _Float16* __restrict__ Pc3, _Float16* __restrict__ Ps3) {
  __shared__ __align__(16) _Float16 As[2 * 4096];
  __shared__ __align__(16) _Float16 Bs[4096];
  if ((int)blockIdx.x < 128)
    gemm_dev<2, 512>(As, Bs, blockIdx.x, blockIdx.y, CmTh, SmTh, Y2T, nullptr, Pc2,
                     Ps2, 16384, 0, nullptr, nullptr, 30, 30);
  else
    gemm_dev<2, 512>(As, Bs, blockIdx.x - 128, blockIdx.y, CmTh, SmTh, Y3T, nullptr,
                     Pc3, Ps3, 8192, 0, nullptr, nullptr, 30, 30);
}

// ---------------- MFMA demodulation (tables inline, both branches fused) ----
template <int JC>
__device__ void demod_dev(char* smemraw, const _Float16* __restrict__ Pc,
                          const _Float16* __restrict__ Ps,
                          const float* __restrict__ wv, const float* __restrict__ cw,
                          float* __restrict__ out, int coff) {
  constexpr int K2 = 2 * JC;
  constexpr int ST = K2 + 8;
  _Float16* Bs = (_Float16*)smemraw;                          // 256*ST
  _Float16* At = (_Float16*)(smemraw + (size_t)256 * ST * 2); // 64*ST
  const int tid = threadIdx.x;
  const int lane = tid & 63;
  const int wid = tid >> 6;
  const int vp = blockIdx.y;
  const int l0 = blockIdx.x * 256;
  {  // stage P transposed
    constexpr int CPL = 64 / K2;
    int r = lane & (K2 - 1);
    int chunk = wid * CPL + (CPL == 1 ? 0 : (lane >> 5));
    int lb = chunk * K2;
    const _Float16* src = (r < JC ? Pc + (size_t)vp * (JC * 512) + r * 512
                                  : Ps + (size_t)vp * (JC * 512) + (r - JC) * 512) +
                          l0 + lb;
#pragma unroll
    for (int i = 0; i < K2 / 8; i++) {
      h8 v = *(const h8*)(src + i * 8);
#pragma unroll
      for (int e = 0; e < 8; e++) Bs[(lb + i * 8 + e) * ST + r] = v[e];
    }
  }
  for (int idx = tid; idx < 64 * K2; idx += 256) {  // tables, trig inline
    int kk = idx & (K2 - 1), m = idx / K2;
    int ab = m >> 5, u = m & 31;
    int n = ab ? ((u << 10) + 1023 - vp) : ((u << 10) + vp);
    int twon = 2 * n + 1;
    float val;
    if (kk < JC) {
      int a = (kk * twon) & 131071;
      val = cosf((float)(a * (PI_D / 65536.0)));
    } else {
      int a = ((kk - JC) * twon) & 131071;
      float sv = sinf((float)(a * (PI_D / 65536.0)));
      val = ab ? sv : -sv;
    }
    At[m * ST + kk] = (_Float16)val;
  }
  __syncthreads();
  const int fm = lane & 15, fko = (lane >> 4) * 8;
  f4 acc[4][4] = {};
#pragma unroll
  for (int ks = 0; ks < K2 / 32; ks++) {
    int ko = ks * 32 + fko;
    h8 af[4], bf[4];
#pragma unroll
    for (int i = 0; i < 4; i++) af[i] = *(const h8*)&At[(i * 16 + fm) * ST + ko];
#pragma unroll
    for (int j = 0; j < 4; j++) bf[j] = *(const h8*)&Bs[(wid * 64 + j * 16 + fm) * ST + ko];
#pragma unroll
    for (int i = 0; i < 4; i++)
#pragma unroll
      for (int j = 0; j < 4; j++) acc[i][j] = MFMA16(af[i], bf[j], acc[i][j]);
  }
  const int er = (lane >> 4) * 4, ec = lane & 15;
#pragma unroll
  for (int i = 0; i < 4; i++)
#pragma unroll
    for (int j = 0; j < 4; j++) {
      int col = l0 + wid * 64 + j * 16 + ec;
      float cl = cw[col];
#pragma unroll
      for (int r = 0; r < 4; r++) {
        int m = i * 16 + er + r;
        int ab = m >> 5, u = m & 31;
        int n = ab ? ((u << 10) + 1023 - vp) : ((u << 10) + vp);
        out[(size_t)n * 1536 + coff + col] = acc[i][j][r] + wv[n] * cl;
      }
    }
}

__global__ __launch_bounds__(256) void demod_pair_k(
    const _Float16* __restrict__ Pc2, const _Float16* __restrict__ Ps2,
    const float* __restrict__ w2v, const float* __restrict__ c2,
    const _Float16* __restrict__ Pc3, const _Float16* __restrict__ Ps3,
    const float* __restrict__ w3v, const float* __restrict__ c3,
    float* __restrict__ out) {
  __shared__ __align__(16) char smem[256 * 72 * 2 + 64 * 72 * 2];  // 46080 B
  if (blockIdx.z == 0)
    demod_dev<32>(smem, Pc2, Ps2, w2v, c2, out, 512);
  else
    demod_dev<16>(smem, Pc3, Ps3, w3v, c3, out, 1024);
}

// ---------------- launch ----------------
extern "C" void kernel_launch(void* const* d_in, const int* in_sizes, int n_in,
                              void* d_out, int out_size, void* d_ws, size_t ws_size,
                              hipStream_t stream) {
  const float* X  = (const float*)d_in[0];
  const float* W1 = (const float*)d_in[1];
  const float* b1 = (const float*)d_in[2];
  const float* W2 = (const float*)d_in[3];
  const float* b2 = (const float*)d_in[4];
  const float* W3 = (const float*)d_in[5];
  const float* b3 = (const float*)d_in[6];
  float* out = (float*)d_out;
  char* w = (char*)d_ws;
  const size_t MB = 1024 * 1024;

  float* F    = (float*)(w);
  float* v1   = (float*)(w + 9 * MB);
  float* w2v  = (float*)(w + 9 * MB + 131072);
  float* w3v  = (float*)(w + 9 * MB + 262144);
  float* c1   = (float*)(w + 9 * MB + 393216);
  float* c2   = (float*)(w + 9 * MB + 395264);
  float* c3   = (float*)(w + 9 * MB + 397312);
  float* Pst  = (float*)(w + 10 * MB);             // 1 MB fp32
  _Float16* CmTh = (_Float16*)(w + 11 * MB);
  _Float16* SmTh = (_Float16*)(w + 11 * MB + 524288);
  _Float16* CSh  = (_Float16*)(w + 12 * MB);       // [512][1024] cos|-sin, 1 MB
  _Float16* M1T  = (_Float16*)(w + 13 * MB);
  _Float16* M2T  = (_Float16*)(w + 13 * MB + 524288);
  _Float16* M3T  = (_Float16*)(w + 14 * MB);
  float* Q2      = (float*)(w + 14 * MB + 524288); // 512 KB fp32
  float* Q3      = (float*)(w + 15 * MB);          // 256 KB fp32
  _Float16* Xh   = (_Float16*)(w + 16 * MB);       // 32 MB
  _Float16* zc   = (_Float16*)(w + 48 * MB);       // 16 MB
  _Float16* zs   = (_Float16*)(w + 64 * MB);       // 16 MB
  _Float16* Pc2h = (_Float16*)(w + 48 * MB);       // over zc (dead)
  _Float16* Ps2h = (_Float16*)(w + 64 * MB);       // over zs (dead)
  _Float16* Pc3h = (_Float16*)(w + 104 * MB);      // 8 MB
  _Float16* Ps3h = (_Float16*)(w + 112 * MB);      // 8 MB, over Zh (dead)
  _Float16* zT   = (_Float16*)(w + 80 * MB);       // [16384][1024], 32 MB (80-112)
  _Float16* Y2T  = (_Float16*)(w + 80 * MB);       // over zT (dead)
  _Float16* Y3T  = (_Float16*)(w + 96 * MB);       // 8 MB over zT (dead)
  _Float16* Zh   = (_Float16*)(w + 112 * MB);      // 16 MB
  _Float16* Y2   = (_Float16*)(w + 128 * MB);      // 16 MB
  _Float16* Y3   = (_Float16*)(w + 144 * MB);      // 8 MB

  // 1. F + tables (CS packed) + rank-1 vectors + c-vectors
  megafill_k<<<2560, 256, 0, stream>>>(F, CSh, CmTh, SmTh, v1, w2v, w3v,
                                       b1, b2, b3, c1, c2, c3);
  // 2. X -> fp16 + sandwich stage 1 (CU-fill packing)
  conv_s1_k<<<16412, 256, 0, stream>>>(X, Xh, W1, W2, W3, F, Pst, Q2, Q3);
  // 3. modulation (Xh fp16, proven path) + sandwich stage 2 (CU-fill packing)
  mod_s2_k<<<1072, 256, 0, stream>>>(Xh, zc, zs, F, Pst, Q2, Q3, M1T, M2T, M3T);
  // 4. zc/zs transpose into stacked zT[16384][1024]
  transpose2_h_k<<<dim3(512, 8), 256, 0, stream>>>(zc, zT, 16384, zs, zT + 512,
                                                   16384, 256, 1024);
  // 5. forward GEMM (K=1024) + independent branch-1 GEMM (CU-fill packing)
  gemm_g1b1_k<<<1536, 256, 0, stream>>>(CSh, zT, Zh, Xh, M1T, out, v1, c1);
  // 6. coefficient GEMMs Y2+Y3
  gemm_duo_k<<<dim3(4, 192), 256, 0, stream>>>(Zh, M2T, M3T, Y2, Y3);
  // 7. Y2/Y3 transpose (fused pair)
  transpose2_h_k<<<dim3(384, 8), 256, 0, stream>>>(Y2, Y2T, 16384, Y3, Y3T, 8192,
                                                   256, 512);
  // 8. inverse shared GEMMs (fused branch2+branch3)
  gemm2_pair_k<<<dim3(192, 4), 256, 0, stream>>>(CmTh, SmTh, Y2T, Y3T, Pc2h, Ps2h,
                                                 Pc3h, Ps3h);
  // 9. demodulation, both branches (tables inline)
  demod_pair_k<<<dim3(2, 512, 2), 256, 0, stream>>>(Pc2h, Ps2h, w2v, c2, Pc3h, Ps3h,
                                                    w3v, c3, out);
}